// Round 7
// baseline (383.916 us; speedup 1.0000x reference)
//
#include <hip/hip_runtime.h>
#include <hip/hip_bf16.h>
#include <math.h>

// MAGNN link prediction forward — fp32 compute; feat table stored bf16.
// Tower: per-wave MFMA GEMM (split-bf16 hi/lo, 3 MFMAs ~ fp32 accuracy), 2-wave col-split.
// binB: LDS counting-sort per coarse bucket (no global atomics, coalesced writes).
// Flash: deferred-rotation packed-f32 online softmax + fused semantic matvec.
#define NN0 20000
#define NN1 20000
#define NTOT 40000
#define FF0 512
#define HIDD 64
#define EEE 200000
#define BBB 8192
#define AVV 128
#define CHH 128

typedef __bf16 bf16x8 __attribute__((ext_vector_type(8)));
typedef __bf16 bf16x4 __attribute__((ext_vector_type(4)));
typedef float f32x4 __attribute__((ext_vector_type(4)));
typedef float f32x2 __attribute__((ext_vector_type(2)));

__device__ __forceinline__ float fast_tanh(float x) {
    float e2 = __expf(2.f * x);
    return 1.f - 2.f / (e2 + 1.f);
}

__device__ __forceinline__ f32x2 bf2_to_f32x2(unsigned int c) {
    f32x2 r;
    r.x = __uint_as_float(c << 16);
    r.y = __uint_as_float(c & 0xffff0000u);
    return r;
}

// ---------------- fused: weight prep (blocks 0..15) + target histogram (rest) ----------------
__global__ __launch_bounds__(256) void prep_hist(
    const float* __restrict__ pw0, const float* __restrict__ pw1,
    const float* __restrict__ w20, const float* __restrict__ w21,
    __bf16* __restrict__ wprep, __bf16* __restrict__ w2prep,
    const int* __restrict__ tgt_user, const int* __restrict__ tgt_item,
    int* __restrict__ cnt)
{
    int bx = blockIdx.x;
    if (bx < 16) {
        int tw = bx & 1, seg = bx >> 1;
        const float* w = tw ? pw1 : pw0;
        __bf16* base = wprep + tw * 65536;
        for (int idx = seg * 4096 + threadIdx.x; idx < (seg + 1) * 4096; idx += 256) {
            int k = idx >> 6, n = idx & 63;
            float v = w[idx];
            __bf16 hi = (__bf16)v;
            __bf16 lo = (__bf16)(v - (float)hi);
            int ks = k >> 5, kb = (k >> 3) & 3, j = k & 7;
            int nt = n >> 4, fr = n & 15;
            int lane = kb * 16 + fr;
            int off = ((ks * 4 + nt) * 64 + lane) * 8 + j;
            base[off] = hi;
            base[32768 + off] = lo;
        }
        const float* w2 = tw ? w21 : w20;
        __bf16* base2 = w2prep + tw * 8192;
        for (int idx = seg * 512 + threadIdx.x; idx < (seg + 1) * 512; idx += 256) {
            int k = idx >> 6, n = idx & 63;
            float v = w2[idx];
            __bf16 hi = (__bf16)v;
            __bf16 lo = (__bf16)(v - (float)hi);
            int ks = k >> 5, kb = (k >> 3) & 3, j = k & 7;
            int nt = n >> 4, fr = n & 15;
            int lane = kb * 16 + fr;
            int off = ((ks * 4 + nt) * 64 + lane) * 8 + j;
            base2[off] = hi;
            base2[4096 + off] = lo;
        }
    } else {
        int flat = bx - 16;                    // 0..3127
        int combo = flat & 3, blk = flat >> 2; // blk 0..781
        const int* tgt = (combo < 2 ? tgt_user : tgt_item) + (long)(combo & 1) * EEE;
        int i = blk * 256 + threadIdx.x;
        if (i < EEE) atomicAdd(&cnt[combo * BBB + tgt[i]], 1);
    }
}

// ---------------- scan: per-combo exclusive prefix over 8192 counters ----------------
__global__ __launch_bounds__(256) void scan_kernel(const int* __restrict__ cnt, int* __restrict__ offs,
                                                   int* __restrict__ cur32, float* __restrict__ s_acc)
{
    int pth = blockIdx.x;
    if (pth == 0 && threadIdx.x < 4) s_acc[threadIdx.x] = 0.f;
    const int* c = cnt + pth * BBB;
    int* o = offs + pth * (BBB + 1);
    __shared__ int part[256];
    int tid = threadIdx.x;
    int base = tid * 32;
    int local[32];
    int sum = 0;
    for (int j = 0; j < 32; j++) { local[j] = sum; sum += c[base + j]; }
    part[tid] = sum;
    __syncthreads();
    for (int d = 1; d < 256; d <<= 1) {
        int v = (tid >= d) ? part[tid - d] : 0;
        __syncthreads();
        part[tid] += v;
        __syncthreads();
    }
    int pre = (tid == 0) ? 0 : part[tid - 1];
    for (int j = 0; j < 32; j++) {
        int val = pre + local[j];
        o[base + j] = val;
        if (((base + j) & 255) == 0) cur32[pth * 32 + ((base + j) >> 8)] = val;
    }
    if (tid == 255) o[BBB] = pre + sum;
}

// ---------------- fused: tower MFMA (blocks 0..2499) + binA coarse binning (rest) ----------------
#define CHUNKF 1024
__global__ __launch_bounds__(128) void tower_binA(
    const float* __restrict__ x0, const float* __restrict__ x1,
    const __bf16* __restrict__ wprep, const __bf16* __restrict__ w2prep,
    const float* __restrict__ pb0, const float* __restrict__ pb1,
    const float* __restrict__ b20, const float* __restrict__ b21,
    const float* __restrict__ g0, const float* __restrict__ g1,
    const float* __restrict__ be0, const float* __restrict__ be1,
    const int* __restrict__ idxa, const int* __restrict__ idxb,
    __hip_bfloat16* __restrict__ feat,
    const int* __restrict__ tgt_user, const int* __restrict__ tgt_item,
    const int* __restrict__ emi_user, const int* __restrict__ emi_item,
    int* __restrict__ cur32, ushort4* __restrict__ binbuf)
{
    __shared__ __align__(16) char pool[8960];
    int bx = blockIdx.x;
    if (bx < 2500) {
        int tile = bx >> 1, tw = bx & 1;
        const float* x  = tw ? x1 : x0;
        const float* pb = tw ? pb1 : pb0;
        const float* b2 = tw ? b21 : b20;
        const float* g  = tw ? g1 : g0;
        const float* be = tw ? be1 : be0;
        const int* idx  = tw ? idxb : idxa;
        float (*hs)[68] = (float(*)[68])pool;          // 4352B
        float* pq  = (float*)(pool + 4352);            // [2][16]
        float* pq2 = (float*)(pool + 4480);            // [2][16]

        int wv = threadIdx.x >> 6;                     // wave 0/1: cols 32wv..32wv+31
        int l = threadIdx.x & 63;
        int fr = l & 15, kb = l >> 4;
        int nt0 = 2 * wv;
        int row0 = tile * 16;
        const float* xp = x + (long)(row0 + fr) * FF0 + kb * 8;
        const __bf16* bp = wprep + tw * 65536;

        f32x4 acc[2];
#pragma unroll
        for (int n2 = 0; n2 < 2; n2++) acc[n2] = (f32x4){0.f, 0.f, 0.f, 0.f};

        float4 a0c, a1c, a0n, a1n;
        bf16x8 bhc[2], blc[2], bhn[2], bln[2];

        a0c = *(const float4*)xp;
        a1c = *(const float4*)(xp + 4);
#pragma unroll
        for (int n2 = 0; n2 < 2; n2++) {
            bhc[n2] = *(const bf16x8*)(bp + ((nt0 + n2) * 64 + l) * 8);
            blc[n2] = *(const bf16x8*)(bp + 32768 + ((nt0 + n2) * 64 + l) * 8);
        }

#pragma unroll 2
        for (int ks = 0; ks < 16; ks++) {
            if (ks + 1 < 16) {
                a0n = *(const float4*)(xp + (ks + 1) * 32);
                a1n = *(const float4*)(xp + (ks + 1) * 32 + 4);
#pragma unroll
                for (int n2 = 0; n2 < 2; n2++) {
                    bhn[n2] = *(const bf16x8*)(bp + (((ks + 1) * 4 + nt0 + n2) * 64 + l) * 8);
                    bln[n2] = *(const bf16x8*)(bp + 32768 + (((ks + 1) * 4 + nt0 + n2) * 64 + l) * 8);
                }
            }
            float av[8] = {a0c.x, a0c.y, a0c.z, a0c.w, a1c.x, a1c.y, a1c.z, a1c.w};
            bf16x8 ah, al;
#pragma unroll
            for (int j = 0; j < 8; j++) {
                __bf16 h = (__bf16)av[j];
                ah[j] = h;
                al[j] = (__bf16)(av[j] - (float)h);
            }
#pragma unroll
            for (int n2 = 0; n2 < 2; n2++) {
                acc[n2] = __builtin_amdgcn_mfma_f32_16x16x32_bf16(ah, bhc[n2], acc[n2], 0, 0, 0);
                acc[n2] = __builtin_amdgcn_mfma_f32_16x16x32_bf16(al, bhc[n2], acc[n2], 0, 0, 0);
                acc[n2] = __builtin_amdgcn_mfma_f32_16x16x32_bf16(ah, blc[n2], acc[n2], 0, 0, 0);
            }
            a0c = a0n; a1c = a1n;
#pragma unroll
            for (int n2 = 0; n2 < 2; n2++) { bhc[n2] = bhn[n2]; blc[n2] = bln[n2]; }
        }

        // epilogue 1: z = acc + pb; h = gelu(z) -> hs; acc2 = z + b2
        float pbv[2], b2v[2];
#pragma unroll
        for (int n2 = 0; n2 < 2; n2++) {
            pbv[n2] = pb[(nt0 + n2) * 16 + fr];
            b2v[n2] = b2[(nt0 + n2) * 16 + fr];
        }
        f32x4 acc2[2];
#pragma unroll
        for (int n2 = 0; n2 < 2; n2++) {
#pragma unroll
            for (int j = 0; j < 4; j++) {
                float z = acc[n2][j] + pbv[n2];
                float h = 0.5f * z * (1.f + erff(z * 0.70710678118654752f));
                hs[kb * 4 + j][(nt0 + n2) * 16 + fr] = h;
                acc2[n2][j] = z + b2v[n2];
            }
        }
        __syncthreads();

        // GEMM2 (MFMA): y = h@w2 + b2 + z
        const __bf16* w2p = w2prep + tw * 8192;
#pragma unroll
        for (int ks = 0; ks < 2; ks++) {
            float4 h0 = *(const float4*)&hs[fr][ks * 32 + kb * 8];
            float4 h1 = *(const float4*)&hs[fr][ks * 32 + kb * 8 + 4];
            float hv[8] = {h0.x, h0.y, h0.z, h0.w, h1.x, h1.y, h1.z, h1.w};
            bf16x8 ah, al;
#pragma unroll
            for (int j = 0; j < 8; j++) {
                __bf16 h = (__bf16)hv[j];
                ah[j] = h;
                al[j] = (__bf16)(hv[j] - (float)h);
            }
#pragma unroll
            for (int n2 = 0; n2 < 2; n2++) {
                bf16x8 bh2 = *(const bf16x8*)(w2p + ((ks * 4 + nt0 + n2) * 64 + l) * 8);
                bf16x8 bl2 = *(const bf16x8*)(w2p + 4096 + ((ks * 4 + nt0 + n2) * 64 + l) * 8);
                acc2[n2] = __builtin_amdgcn_mfma_f32_16x16x32_bf16(ah, bh2, acc2[n2], 0, 0, 0);
                acc2[n2] = __builtin_amdgcn_mfma_f32_16x16x32_bf16(al, bh2, acc2[n2], 0, 0, 0);
                acc2[n2] = __builtin_amdgcn_mfma_f32_16x16x32_bf16(ah, bl2, acc2[n2], 0, 0, 0);
            }
        }

        // LayerNorm: cross-wave partials via LDS
        float pj[4];
#pragma unroll
        for (int j = 0; j < 4; j++) {
            float p = acc2[0][j] + acc2[1][j];
            p += __shfl_xor(p, 1); p += __shfl_xor(p, 2);
            p += __shfl_xor(p, 4); p += __shfl_xor(p, 8);
            pj[j] = p;
        }
        if (fr == 0) {
#pragma unroll
            for (int j = 0; j < 4; j++) pq[wv * 16 + kb * 4 + j] = pj[j];
        }
        __syncthreads();
        float mu[4];
#pragma unroll
        for (int j = 0; j < 4; j++)
            mu[j] = (pj[j] + pq[(wv ^ 1) * 16 + kb * 4 + j]) * (1.f / 64.f);
        float d[2][4], vj[4];
#pragma unroll
        for (int j = 0; j < 4; j++) {
            d[0][j] = acc2[0][j] - mu[j];
            d[1][j] = acc2[1][j] - mu[j];
            float v = d[0][j] * d[0][j] + d[1][j] * d[1][j];
            v += __shfl_xor(v, 1); v += __shfl_xor(v, 2);
            v += __shfl_xor(v, 4); v += __shfl_xor(v, 8);
            vj[j] = v;
        }
        if (fr == 0) {
#pragma unroll
            for (int j = 0; j < 4; j++) pq2[wv * 16 + kb * 4 + j] = vj[j];
        }
        __syncthreads();
        float gv[2], bev[2];
#pragma unroll
        for (int n2 = 0; n2 < 2; n2++) {
            gv[n2] = g[(nt0 + n2) * 16 + fr];
            bev[n2] = be[(nt0 + n2) * 16 + fr];
        }
#pragma unroll
        for (int j = 0; j < 4; j++) {
            float var = (vj[j] + pq2[(wv ^ 1) * 16 + kb * 4 + j]) * (1.f / 64.f);
            float is = 1.f / sqrtf(var + 1e-5f);
#pragma unroll
            for (int n2 = 0; n2 < 2; n2++)
                hs[kb * 4 + j][(nt0 + n2) * 16 + fr] = d[n2][j] * is * gv[n2] + bev[n2];
        }
        __syncthreads();
#pragma unroll
        for (int r = 0; r < 8; r++) {
            int rr = wv * 8 + r;
            feat[(long)idx[row0 + rr] * HIDD + l] = __float2bfloat16(hs[rr][l]);
        }
    } else {
        int flat = bx - 2500;
        int combo = flat & 3;
        int base = (flat >> 2) * CHUNKF;
        const int* tgt = (combo < 2 ? tgt_user : tgt_item) + (long)(combo & 1) * EEE;
        const int* emi = (combo < 2 ? emi_user : emi_item) + (long)(combo & 1) * EEE * 3;
        ushort4* sbuf = (ushort4*)pool;                 // 8192B
        int* lcnt  = (int*)(pool + 8192);
        int* lofs  = lcnt + 32;
        int* gbase = lofs + 33;
        int* lcur  = gbase + 32;
        int tid = threadIdx.x;
        if (tid < 32) { lcnt[tid] = 0; lcur[tid] = 0; }
        __syncthreads();
        ushort4 ent[8]; int bk[8];
#pragma unroll
        for (int ps = 0; ps < 8; ps++) {
            int i = base + ps * 128 + tid;
            if (i < EEE) {
                int t = tgt[i];
                ent[ps] = make_ushort4((unsigned short)emi[3 * i], (unsigned short)emi[3 * i + 1],
                                       (unsigned short)emi[3 * i + 2], (unsigned short)t);
                bk[ps] = t >> 8;
                atomicAdd(&lcnt[bk[ps]], 1);
            } else bk[ps] = -1;
        }
        __syncthreads();
        if (tid == 0) {
            int run = 0;
            for (int k = 0; k < 32; k++) { lofs[k] = run; run += lcnt[k]; }
            lofs[32] = run;
        }
        __syncthreads();
        if (tid < 32) gbase[tid] = atomicAdd(&cur32[combo * 32 + tid], lcnt[tid]);
        __syncthreads();
#pragma unroll
        for (int ps = 0; ps < 8; ps++) {
            if (bk[ps] >= 0) {
                int pos = lofs[bk[ps]] + atomicAdd(&lcur[bk[ps]], 1);
                sbuf[pos] = ent[ps];
            }
        }
        __syncthreads();
        int total = lofs[32];
        ushort4* dst = binbuf + (long)combo * EEE;
        for (int j = tid; j < total; j += 128) {
            ushort4 e = sbuf[j];
            int k = e.w >> 8;
            dst[gbase[k] + (j - lofs[k])] = e;
        }
    }
}

// ---------------- binB: LDS counting-sort per coarse bucket ----------------
// Block = (bucket k, combo). Bucket = 256 consecutive targets, ~6250 entries (~50KB).
// Local target counts == global counts, so LDS-sorted layout == CSR layout at offset of[k<<8].
// No global atomics; output writes fully coalesced.
#define BKCAP 7680
__global__ __launch_bounds__(256) void binB_kernel(
    const int* __restrict__ offs,
    const ushort4* __restrict__ binbuf, ushort4* __restrict__ nodes)
{
    int combo = blockIdx.y;
    int k = blockIdx.x;
    const int* of = offs + combo * (BBB + 1);
    int rbeg = of[k << 8], rend = of[(k + 1) << 8];
    int cnt = rend - rbeg;
    if (cnt > BKCAP) cnt = BKCAP;          // data-safe: 18 sigma above mean
    __shared__ ushort4 sbuf[BKCAP];        // 61440B
    __shared__ int lh[256];                // hist -> excl offsets
    __shared__ int part[256];              // scan scratch -> placement counters
    int tid = threadIdx.x;
    lh[tid] = 0;
    __syncthreads();
    const ushort4* src = binbuf + (long)combo * EEE + rbeg;
    for (int j = tid; j < cnt; j += 256)
        atomicAdd(&lh[src[j].w & 255], 1);
    __syncthreads();
    int myc = lh[tid];
    part[tid] = myc;
    __syncthreads();
    for (int d = 1; d < 256; d <<= 1) {
        int u = (tid >= d) ? part[tid - d] : 0;
        __syncthreads();
        part[tid] += u;
        __syncthreads();
    }
    int myofs = part[tid] - myc;           // exclusive prefix
    __syncthreads();
    lh[tid] = myofs;                       // lh := offsets
    part[tid] = 0;                         // part := placement counters
    __syncthreads();
    for (int j = tid; j < cnt; j += 256) {
        ushort4 e = src[j];
        int b = e.w & 255;
        int pos = lh[b] + atomicAdd(&part[b], 1);
        if (pos < BKCAP) sbuf[pos] = e;
    }
    __syncthreads();
    ushort4* dst = nodes + (long)combo * EEE + rbeg;
    for (int j = tid; j < cnt; j += 256) dst[j] = sbuf[j];
}

// ---------------- flash metapath + fused semantic matvec ----------------
// hidden = (u0 + u2 + R*u1)/3 with deferred rotation; online softmax; ELU.
// Fused sem: contrib = tanh(row @ w1 + b1) @ w2, block-reduced, one atomic per block.
__global__ __launch_bounds__(256) void flash_mp(
    const __hip_bfloat16* __restrict__ feat, const ushort4* __restrict__ nodes,
    const int* __restrict__ offs, const float* __restrict__ r_vec,
    const float* __restrict__ attn_user, const float* __restrict__ attn_item,
    const float* __restrict__ su_w1, const float* __restrict__ su_b1, const float* __restrict__ su_w2,
    const float* __restrict__ si_w1, const float* __restrict__ si_b1, const float* __restrict__ si_w2,
    float* __restrict__ s_acc, float* __restrict__ ret)
{
    __shared__ float sred[4];
    int combo = blockIdx.y;
    int wid = threadIdx.x >> 6, lane = threadIdx.x & 63;
    int half = lane >> 5, p = lane & 31;
    int side = combo >> 1;
    const float* attn = (side == 0 ? attn_user : attn_item) + (combo & 1) * 64;
    const unsigned int* f2 = (const unsigned int*)feat;
    float2 rb = ((const float2*)r_vec)[p];
    float invn = 1.f / sqrtf(rb.x * rb.x + rb.y * rb.y);
    float rvx = rb.x * invn, rvy = rb.y * invn;
    if (side == 0) rvy = -rvy;
    float aRe = attn[2 * p], aIm = attn[2 * p + 1];
    f32x2 av  = { aRe * (1.f / 3.f), aIm * (1.f / 3.f) };
    f32x2 apv = { (rvx * aRe + rvy * aIm) * (1.f / 3.f),
                  (rvx * aIm - rvy * aRe) * (1.f / 3.f) };
    int t = blockIdx.x * 4 + wid;
    const int* of = offs + combo * (BBB + 1);
    int beg = of[t], end = of[t + 1];
    int n = end - beg;
    const ushort4* nd = nodes + (long)combo * EEE;

    float m = -3.4e38f, s = 0.f;
    f32x2 A02 = {0.f, 0.f}, A1 = {0.f, 0.f};

    unsigned int c0[4], c1[4], c2[4];
    ushort4 nq[4];
    if (n > 0) {
#pragma unroll
        for (int q = 0; q < 4; q++) {
            ushort4 a = nd[min(beg + 2 * q + half, EEE - 1)];
            c0[q] = f2[(int)a.x * 32 + p];
            c1[q] = f2[(int)a.y * 32 + p];
            c2[q] = f2[(int)a.z * 32 + p];
        }
#pragma unroll
        for (int q = 0; q < 4; q++)
            nq[q] = nd[min(beg + 8 + 2 * q + half, EEE - 1)];
    }
    for (int it = 0; it < n; it += 8) {
        f32x2 u1[4], v02[4];
        float e[4];
#pragma unroll
        for (int q = 0; q < 4; q++) {
            f32x2 u0 = bf2_to_f32x2(c0[q]);
            u1[q]    = bf2_to_f32x2(c1[q]);
            f32x2 u2 = bf2_to_f32x2(c2[q]);
            v02[q] = u0 + u2;
        }
        if (it + 8 < n) {
#pragma unroll
            for (int q = 0; q < 4; q++) {
                c0[q] = f2[(int)nq[q].x * 32 + p];
                c1[q] = f2[(int)nq[q].y * 32 + p];
                c2[q] = f2[(int)nq[q].z * 32 + p];
            }
#pragma unroll
            for (int q = 0; q < 4; q++)
                nq[q] = nd[min(beg + it + 16 + 2 * q + half, EEE - 1)];
        }
#pragma unroll
        for (int q = 0; q < 4; q++) {
            f32x2 tt = v02[q] * av + u1[q] * apv;
            float pa = tt.x + tt.y;
            pa += __shfl_xor(pa, 1);
            pa += __shfl_xor(pa, 2);
            e[q] = fmaxf(pa, 0.01f * pa);        // leaky_relu
        }
        if (it + 8 > n) {                        // tail chunk only (wave-uniform)
#pragma unroll
            for (int q = 0; q < 4; q++)
                if (it + 2 * q + half >= n) e[q] = -3.4e38f;
        }
        float mx = fmaxf(fmaxf(e[0], e[1]), fmaxf(e[2], e[3]));
        float mn = fmaxf(m, fmaxf(mx, __shfl_xor(mx, 32)));
        float alpha = __expf(m - mn);
        s *= alpha; A02 *= alpha; A1 *= alpha;
        float wl = 0.f;
#pragma unroll
        for (int q = 0; q < 4; q++) {
            float w = __expf(e[q] - mn);
            wl += w;
            A02 += v02[q] * w;
            A1  += u1[q] * w;
        }
        s += wl + __shfl_xor(wl, 32);
        m = mn;
    }
    float Sx = A02.x + __shfl_xor(A02.x, 32);
    float Sy = A02.y + __shfl_xor(A02.y, 32);
    float Tx = A1.x + __shfl_xor(A1.x, 32);
    float Ty = A1.y + __shfl_xor(A1.y, 32);
    float inv = (1.f / 3.f) / (s + 1e-9f);
    float vx = (Sx + rvx * Tx - rvy * Ty) * inv;
    float vy = (Sy + rvx * Ty + rvy * Tx) * inv;
    vx = vx > 0.f ? vx : __expf(vx) - 1.f;       // ELU
    vy = vy > 0.f ? vy : __expf(vy) - 1.f;
    if (half == 0)
        ((float2*)ret)[((long)combo * BBB + t) * 32 + p] = make_float2(vx, vy);

    // ---- fused semantic matvec: lane owns cols 2*lane, 2*lane+1 of AV=128 ----
    const float* w1 = side ? si_w1 : su_w1;
    const float* b1 = side ? si_b1 : su_b1;
    const float* w2s = side ? si_w2 : su_w2;
    float2 b1v = ((const float2*)b1)[lane];
    float h0 = b1v.x, h1 = b1v.y;
#pragma unroll 8
    for (int p2 = 0; p2 < 32; p2++) {
        float rx = __shfl(vx, p2);               // row[2*p2]
        float ry = __shfl(vy, p2);               // row[2*p2+1]
        float2 wa = ((const float2*)(w1 + (2 * p2) * AVV))[lane];
        float2 wb = ((const float2*)(w1 + (2 * p2 + 1) * AVV))[lane];
        h0 = fmaf(rx, wa.x, h0); h1 = fmaf(rx, wa.y, h1);
        h0 = fmaf(ry, wb.x, h0); h1 = fmaf(ry, wb.y, h1);
    }
    float2 w2v = ((const float2*)w2s)[lane];
    float contrib = fast_tanh(h0) * w2v.x + fast_tanh(h1) * w2v.y;
    for (int off = 32; off; off >>= 1) contrib += __shfl_xor(contrib, off);
    if (lane == 0) sred[wid] = contrib;
    __syncthreads();
    if (threadIdx.x == 0)
        atomicAdd(&s_acc[combo], sred[0] + sred[1] + sred[2] + sred[3]);
}

// ---------------- final product MLP + softmax (beta inline, GEMM-tiled) ----------------
__global__ __launch_bounds__(256) void final_kernel(
    const float* __restrict__ ret, const float* __restrict__ s_acc,
    const float* __restrict__ cw1, const float* __restrict__ cb1, const float* __restrict__ cw2,
    float* __restrict__ outp)
{
    float s0 = s_acc[0] * (1.f / BBB), s1 = s_acc[1] * (1.f / BBB);
    float s2 = s_acc[2] * (1.f / BBB), s3 = s_acc[3] * (1.f / BBB);
    float mu = fmaxf(s0, s1);
    float e0 = __expf(s0 - mu), e1 = __expf(s1 - mu);
    float bu0 = e0 / (e0 + e1), bu1 = e1 / (e0 + e1);
    float mi = fmaxf(s2, s3);
    float f0 = __expf(s2 - mi), f1 = __expf(s3 - mi);
    float bi0 = f0 / (f0 + f1), bi1 = f1 / (f0 + f1);

    __shared__ float xsld[64][68];
    __shared__ float w1s[64][128];
    int tid = threadIdx.x;
    int rowbase = blockIdx.x * 64;
    const float4* r4 = (const float4*)ret;
    for (int li = tid; li < 1024; li += 256) {
        int r = li >> 4, c4 = li & 15;
        float4 a = r4[((long)0 * BBB + rowbase + r) * 16 + c4];
        float4 b = r4[((long)1 * BBB + rowbase + r) * 16 + c4];
        float4 cc = r4[((long)2 * BBB + rowbase + r) * 16 + c4];
        float4 d = r4[((long)3 * BBB + rowbase + r) * 16 + c4];
        float4 xv;
        xv.x = (bu0 * a.x + bu1 * b.x) * (bi0 * cc.x + bi1 * d.x);
        xv.y = (bu0 * a.y + bu1 * b.y) * (bi0 * cc.y + bi1 * d.y);
        xv.z = (bu0 * a.z + bu1 * b.z) * (bi0 * cc.z + bi1 * d.z);
        xv.w = (bu0 * a.w + bu1 * b.w) * (bi0 * cc.w + bi1 * d.w);
        *(float4*)&xsld[r][c4 * 4] = xv;
    }
    const float4* w14 = (const float4*)cw1;
    for (int li = tid; li < 2048; li += 256) {
        float4 v = w14[li];
        *(float4*)&w1s[li >> 5][(li & 31) * 4] = v;
    }
    __syncthreads();
    int ct = tid & 15, rt = tid >> 4;
    float acc[4][8];
#pragma unroll
    for (int cc = 0; cc < 8; cc++) {
        float b = cb1[8 * ct + cc];
#pragma unroll
        for (int j = 0; j < 4; j++) acc[j][cc] = b;
    }
    for (int k = 0; k < 64; k += 4) {
        float4 xv[4];
#pragma unroll
        for (int j = 0; j < 4; j++) xv[j] = *(const float4*)&xsld[4 * rt + j][k];
#pragma unroll
        for (int kk = 0; kk < 4; kk++) {
            float4 wv0 = *(const float4*)&w1s[k + kk][8 * ct];
            float4 wv1 = *(const float4*)&w1s[k + kk][8 * ct + 4];
#pragma unroll
            for (int j = 0; j < 4; j++) {
                float xx = kk == 0 ? xv[j].x : kk == 1 ? xv[j].y : kk == 2 ? xv[j].z : xv[j].w;
                acc[j][0] = fmaf(xx, wv0.x, acc[j][0]);
                acc[j][1] = fmaf(xx, wv0.y, acc[j][1]);
                acc[j][2] = fmaf(xx, wv0.z, acc[j][2]);
                acc[j][3] = fmaf(xx, wv0.w, acc[j][3]);
                acc[j][4] = fmaf(xx, wv1.x, acc[j][4]);
                acc[j][5] = fmaf(xx, wv1.y, acc[j][5]);
                acc[j][6] = fmaf(xx, wv1.z, acc[j][6]);
                acc[j][7] = fmaf(xx, wv1.w, acc[j][7]);
            }
        }
    }
    float pp0[4], pp1[4];
#pragma unroll
    for (int j = 0; j < 4; j++) { pp0[j] = 0.f; pp1[j] = 0.f; }
#pragma unroll
    for (int cc = 0; cc < 8; cc++) {
        int col = 8 * ct + cc;
        float c0 = cw2[col * 2], c1 = cw2[col * 2 + 1];
#pragma unroll
        for (int j = 0; j < 4; j++) {
            float h = fmaxf(acc[j][cc], 0.f);
            pp0[j] = fmaf(h, c0, pp0[j]);
            pp1[j] = fmaf(h, c1, pp1[j]);
        }
    }
    __syncthreads();
    float2* red = (float2*)xsld;
#pragma unroll
    for (int j = 0; j < 4; j++)
        red[(4 * rt + j) * 16 + ct] = make_float2(pp0[j], pp1[j]);
    __syncthreads();
    if (tid < 64) {
        float q0 = 0.f, q1 = 0.f;
        for (int i = 0; i < 16; i++) {
            float2 e = red[tid * 16 + i];
            q0 += e.x; q1 += e.y;
        }
        float mx = fmaxf(q0, q1);
        float a0 = __expf(q0 - mx), a1 = __expf(q1 - mx);
        float dn = a0 + a1;
        outp[(rowbase + tid) * 2] = a0 / dn;
        outp[(rowbase + tid) * 2 + 1] = a1 / dn;
    }
}

extern "C" void kernel_launch(void* const* d_in, const int* in_sizes, int n_in,
                              void* d_out, int out_size, void* d_ws, size_t ws_size,
                              hipStream_t stream)
{
    const float* feats0 = (const float*)d_in[0];
    const float* feats1 = (const float*)d_in[1];
    const float* t0_pw = (const float*)d_in[2];
    const float* t0_pb = (const float*)d_in[3];
    const float* t0_w2 = (const float*)d_in[4];
    const float* t0_b2 = (const float*)d_in[5];
    const float* t0_g  = (const float*)d_in[6];
    const float* t0_be = (const float*)d_in[7];
    const float* t1_pw = (const float*)d_in[8];
    const float* t1_pb = (const float*)d_in[9];
    const float* t1_w2 = (const float*)d_in[10];
    const float* t1_b2 = (const float*)d_in[11];
    const float* t1_g  = (const float*)d_in[12];
    const float* t1_be = (const float*)d_in[13];
    const float* r_vec = (const float*)d_in[14];
    const float* attn_user = (const float*)d_in[15];
    const float* attn_item = (const float*)d_in[16];
    const float* su_w1 = (const float*)d_in[17];
    const float* su_b1 = (const float*)d_in[18];
    const float* su_w2 = (const float*)d_in[19];
    const float* si_w1 = (const float*)d_in[20];
    const float* si_b1 = (const float*)d_in[21];
    const float* si_w2 = (const float*)d_in[22];
    const float* cw1 = (const float*)d_in[23];
    const float* cb1 = (const float*)d_in[24];
    const float* cw2 = (const float*)d_in[25];
    const int* idx0 = (const int*)d_in[26];
    const int* idx1 = (const int*)d_in[27];
    const int* emi_user = (const int*)d_in[28];
    const int* tgt_user = (const int*)d_in[29];
    const int* emi_item = (const int*)d_in[30];
    const int* tgt_item = (const int*)d_in[31];
    float* outp = (float*)d_out;

    // workspace layout (256B aligned)
    char* ws = (char*)d_ws;
    __hip_bfloat16* feat = (__hip_bfloat16*)(ws + 0);   // 5,120,000
    int*     cnt    = (int*)(ws + 5120000);             // 131,072
    int*     cur32  = (int*)(ws + 5382144);             // 512
    int*     offs   = (int*)(ws + 5382656);             // 131,088 -> pad 131,328
    float*   s_acc  = (float*)(ws + 5513984);           // 256
    ushort4* binbuf = (ushort4*)(ws + 5514240);         // 6,400,000
    ushort4* nodes  = (ushort4*)(ws + 11914240);        // 6,400,000
    float*   ret_buf= (float*)(ws + 18314240);          // 8,388,608
    __bf16*  wprep  = (__bf16*)(ws + 26702848);         // 262,144  (end ~27.0 MB)
    // w2prep (32KB) aliases the start of `nodes`: written by prep_hist, read by tower
    // (tower_binA), then overwritten by binB which runs strictly after. binA writes
    // only binbuf, so the concurrent tower reads are race-free.
    __bf16*  w2prep = (__bf16*)(ws + 11914240);

    hipMemsetAsync(cnt, 0, 4 * BBB * sizeof(int), stream);

    prep_hist<<<16 + 4 * ((EEE + 255) / 256), 256, 0, stream>>>(
        t0_pw, t1_pw, t0_w2, t1_w2, wprep, w2prep, tgt_user, tgt_item, cnt);

    scan_kernel<<<4, 256, 0, stream>>>(cnt, offs, cur32, s_acc);

    tower_binA<<<2500 + 4 * ((EEE + CHUNKF - 1) / CHUNKF), 128, 0, stream>>>(
        feats0, feats1, wprep, w2prep, t0_pb, t1_pb,
        t0_b2, t1_b2, t0_g, t1_g, t0_be, t1_be, idx0, idx1, feat,
        tgt_user, tgt_item, emi_user, emi_item, cur32, binbuf);

    binB_kernel<<<dim3(32, 4), 256, 0, stream>>>(offs, binbuf, nodes);

    flash_mp<<<dim3(BBB / 4, 4), 256, 0, stream>>>(feat, nodes, offs, r_vec,
                                                   attn_user, attn_item,
                                                   su_w1, su_b1, su_w2,
                                                   si_w1, si_b1, si_w2,
                                                   s_acc, ret_buf);

    final_kernel<<<BBB / 64, 256, 0, stream>>>(ret_buf, s_acc, cw1, cb1, cw2, outp);
}

// Round 8
// 327.838 us; speedup vs baseline: 1.1711x; 1.1711x over previous
//
#include <hip/hip_runtime.h>
#include <hip/hip_bf16.h>
#include <math.h>

// MAGNN link prediction forward — fp32 compute; feat table stored bf16.
// Tower: per-wave MFMA GEMM (split-bf16 hi/lo, 3 MFMAs ~ fp32 accuracy), 2-wave col-split.
// binB: LDS counting-sort per coarse bucket (no global atomics, coalesced writes).
// Flash: deferred-rotation packed-f32 online softmax. Sem: standalone GEMM-tiled kernel
// (r7 post-mortem: fusing sem into flash re-read w1 per-wave = +60us; reverted).
#define NN0 20000
#define NN1 20000
#define NTOT 40000
#define FF0 512
#define HIDD 64
#define EEE 200000
#define BBB 8192
#define AVV 128
#define CHH 128

typedef __bf16 bf16x8 __attribute__((ext_vector_type(8)));
typedef __bf16 bf16x4 __attribute__((ext_vector_type(4)));
typedef float f32x4 __attribute__((ext_vector_type(4)));
typedef float f32x2 __attribute__((ext_vector_type(2)));

__device__ __forceinline__ float fast_tanh(float x) {
    float e2 = __expf(2.f * x);
    return 1.f - 2.f / (e2 + 1.f);
}

__device__ __forceinline__ f32x2 bf2_to_f32x2(unsigned int c) {
    f32x2 r;
    r.x = __uint_as_float(c << 16);
    r.y = __uint_as_float(c & 0xffff0000u);
    return r;
}

// ---------------- fused: weight prep (blocks 0..15) + target histogram (rest) ----------------
__global__ __launch_bounds__(256) void prep_hist(
    const float* __restrict__ pw0, const float* __restrict__ pw1,
    const float* __restrict__ w20, const float* __restrict__ w21,
    __bf16* __restrict__ wprep, __bf16* __restrict__ w2prep,
    const int* __restrict__ tgt_user, const int* __restrict__ tgt_item,
    int* __restrict__ cnt)
{
    int bx = blockIdx.x;
    if (bx < 16) {
        int tw = bx & 1, seg = bx >> 1;
        const float* w = tw ? pw1 : pw0;
        __bf16* base = wprep + tw * 65536;
        for (int idx = seg * 4096 + threadIdx.x; idx < (seg + 1) * 4096; idx += 256) {
            int k = idx >> 6, n = idx & 63;
            float v = w[idx];
            __bf16 hi = (__bf16)v;
            __bf16 lo = (__bf16)(v - (float)hi);
            int ks = k >> 5, kb = (k >> 3) & 3, j = k & 7;
            int nt = n >> 4, fr = n & 15;
            int lane = kb * 16 + fr;
            int off = ((ks * 4 + nt) * 64 + lane) * 8 + j;
            base[off] = hi;
            base[32768 + off] = lo;
        }
        const float* w2 = tw ? w21 : w20;
        __bf16* base2 = w2prep + tw * 8192;
        for (int idx = seg * 512 + threadIdx.x; idx < (seg + 1) * 512; idx += 256) {
            int k = idx >> 6, n = idx & 63;
            float v = w2[idx];
            __bf16 hi = (__bf16)v;
            __bf16 lo = (__bf16)(v - (float)hi);
            int ks = k >> 5, kb = (k >> 3) & 3, j = k & 7;
            int nt = n >> 4, fr = n & 15;
            int lane = kb * 16 + fr;
            int off = ((ks * 4 + nt) * 64 + lane) * 8 + j;
            base2[off] = hi;
            base2[4096 + off] = lo;
        }
    } else {
        int flat = bx - 16;                    // 0..3127
        int combo = flat & 3, blk = flat >> 2; // blk 0..781
        const int* tgt = (combo < 2 ? tgt_user : tgt_item) + (long)(combo & 1) * EEE;
        int i = blk * 256 + threadIdx.x;
        if (i < EEE) atomicAdd(&cnt[combo * BBB + tgt[i]], 1);
    }
}

// ---------------- scan: per-combo exclusive prefix over 8192 counters ----------------
__global__ __launch_bounds__(256) void scan_kernel(const int* __restrict__ cnt, int* __restrict__ offs,
                                                   int* __restrict__ cur32, float* __restrict__ s_acc)
{
    int pth = blockIdx.x;
    if (pth == 0 && threadIdx.x < 4) s_acc[threadIdx.x] = 0.f;
    const int* c = cnt + pth * BBB;
    int* o = offs + pth * (BBB + 1);
    __shared__ int part[256];
    int tid = threadIdx.x;
    int base = tid * 32;
    int local[32];
    int sum = 0;
    for (int j = 0; j < 32; j++) { local[j] = sum; sum += c[base + j]; }
    part[tid] = sum;
    __syncthreads();
    for (int d = 1; d < 256; d <<= 1) {
        int v = (tid >= d) ? part[tid - d] : 0;
        __syncthreads();
        part[tid] += v;
        __syncthreads();
    }
    int pre = (tid == 0) ? 0 : part[tid - 1];
    for (int j = 0; j < 32; j++) {
        int val = pre + local[j];
        o[base + j] = val;
        if (((base + j) & 255) == 0) cur32[pth * 32 + ((base + j) >> 8)] = val;
    }
    if (tid == 255) o[BBB] = pre + sum;
}

// ---------------- fused: tower MFMA (blocks 0..2499) + binA coarse binning (rest) ----------------
#define CHUNKF 1024
__global__ __launch_bounds__(128) void tower_binA(
    const float* __restrict__ x0, const float* __restrict__ x1,
    const __bf16* __restrict__ wprep, const __bf16* __restrict__ w2prep,
    const float* __restrict__ pb0, const float* __restrict__ pb1,
    const float* __restrict__ b20, const float* __restrict__ b21,
    const float* __restrict__ g0, const float* __restrict__ g1,
    const float* __restrict__ be0, const float* __restrict__ be1,
    const int* __restrict__ idxa, const int* __restrict__ idxb,
    __hip_bfloat16* __restrict__ feat,
    const int* __restrict__ tgt_user, const int* __restrict__ tgt_item,
    const int* __restrict__ emi_user, const int* __restrict__ emi_item,
    int* __restrict__ cur32, ushort4* __restrict__ binbuf)
{
    __shared__ __align__(16) char pool[8960];
    int bx = blockIdx.x;
    if (bx < 2500) {
        int tile = bx >> 1, tw = bx & 1;
        const float* x  = tw ? x1 : x0;
        const float* pb = tw ? pb1 : pb0;
        const float* b2 = tw ? b21 : b20;
        const float* g  = tw ? g1 : g0;
        const float* be = tw ? be1 : be0;
        const int* idx  = tw ? idxb : idxa;
        float (*hs)[68] = (float(*)[68])pool;          // 4352B
        float* pq  = (float*)(pool + 4352);            // [2][16]
        float* pq2 = (float*)(pool + 4480);            // [2][16]

        int wv = threadIdx.x >> 6;                     // wave 0/1: cols 32wv..32wv+31
        int l = threadIdx.x & 63;
        int fr = l & 15, kb = l >> 4;
        int nt0 = 2 * wv;
        int row0 = tile * 16;
        const float* xp = x + (long)(row0 + fr) * FF0 + kb * 8;
        const __bf16* bp = wprep + tw * 65536;

        f32x4 acc[2];
#pragma unroll
        for (int n2 = 0; n2 < 2; n2++) acc[n2] = (f32x4){0.f, 0.f, 0.f, 0.f};

        float4 a0c, a1c, a0n, a1n;
        bf16x8 bhc[2], blc[2], bhn[2], bln[2];

        a0c = *(const float4*)xp;
        a1c = *(const float4*)(xp + 4);
#pragma unroll
        for (int n2 = 0; n2 < 2; n2++) {
            bhc[n2] = *(const bf16x8*)(bp + ((nt0 + n2) * 64 + l) * 8);
            blc[n2] = *(const bf16x8*)(bp + 32768 + ((nt0 + n2) * 64 + l) * 8);
        }

#pragma unroll 2
        for (int ks = 0; ks < 16; ks++) {
            if (ks + 1 < 16) {
                a0n = *(const float4*)(xp + (ks + 1) * 32);
                a1n = *(const float4*)(xp + (ks + 1) * 32 + 4);
#pragma unroll
                for (int n2 = 0; n2 < 2; n2++) {
                    bhn[n2] = *(const bf16x8*)(bp + (((ks + 1) * 4 + nt0 + n2) * 64 + l) * 8);
                    bln[n2] = *(const bf16x8*)(bp + 32768 + (((ks + 1) * 4 + nt0 + n2) * 64 + l) * 8);
                }
            }
            float av[8] = {a0c.x, a0c.y, a0c.z, a0c.w, a1c.x, a1c.y, a1c.z, a1c.w};
            bf16x8 ah, al;
#pragma unroll
            for (int j = 0; j < 8; j++) {
                __bf16 h = (__bf16)av[j];
                ah[j] = h;
                al[j] = (__bf16)(av[j] - (float)h);
            }
#pragma unroll
            for (int n2 = 0; n2 < 2; n2++) {
                acc[n2] = __builtin_amdgcn_mfma_f32_16x16x32_bf16(ah, bhc[n2], acc[n2], 0, 0, 0);
                acc[n2] = __builtin_amdgcn_mfma_f32_16x16x32_bf16(al, bhc[n2], acc[n2], 0, 0, 0);
                acc[n2] = __builtin_amdgcn_mfma_f32_16x16x32_bf16(ah, blc[n2], acc[n2], 0, 0, 0);
            }
            a0c = a0n; a1c = a1n;
#pragma unroll
            for (int n2 = 0; n2 < 2; n2++) { bhc[n2] = bhn[n2]; blc[n2] = bln[n2]; }
        }

        // epilogue 1: z = acc + pb; h = gelu(z) -> hs; acc2 = z + b2
        float pbv[2], b2v[2];
#pragma unroll
        for (int n2 = 0; n2 < 2; n2++) {
            pbv[n2] = pb[(nt0 + n2) * 16 + fr];
            b2v[n2] = b2[(nt0 + n2) * 16 + fr];
        }
        f32x4 acc2[2];
#pragma unroll
        for (int n2 = 0; n2 < 2; n2++) {
#pragma unroll
            for (int j = 0; j < 4; j++) {
                float z = acc[n2][j] + pbv[n2];
                float h = 0.5f * z * (1.f + erff(z * 0.70710678118654752f));
                hs[kb * 4 + j][(nt0 + n2) * 16 + fr] = h;
                acc2[n2][j] = z + b2v[n2];
            }
        }
        __syncthreads();

        // GEMM2 (MFMA): y = h@w2 + b2 + z
        const __bf16* w2p = w2prep + tw * 8192;
#pragma unroll
        for (int ks = 0; ks < 2; ks++) {
            float4 h0 = *(const float4*)&hs[fr][ks * 32 + kb * 8];
            float4 h1 = *(const float4*)&hs[fr][ks * 32 + kb * 8 + 4];
            float hv[8] = {h0.x, h0.y, h0.z, h0.w, h1.x, h1.y, h1.z, h1.w};
            bf16x8 ah, al;
#pragma unroll
            for (int j = 0; j < 8; j++) {
                __bf16 h = (__bf16)hv[j];
                ah[j] = h;
                al[j] = (__bf16)(hv[j] - (float)h);
            }
#pragma unroll
            for (int n2 = 0; n2 < 2; n2++) {
                bf16x8 bh2 = *(const bf16x8*)(w2p + ((ks * 4 + nt0 + n2) * 64 + l) * 8);
                bf16x8 bl2 = *(const bf16x8*)(w2p + 4096 + ((ks * 4 + nt0 + n2) * 64 + l) * 8);
                acc2[n2] = __builtin_amdgcn_mfma_f32_16x16x32_bf16(ah, bh2, acc2[n2], 0, 0, 0);
                acc2[n2] = __builtin_amdgcn_mfma_f32_16x16x32_bf16(al, bh2, acc2[n2], 0, 0, 0);
                acc2[n2] = __builtin_amdgcn_mfma_f32_16x16x32_bf16(ah, bl2, acc2[n2], 0, 0, 0);
            }
        }

        // LayerNorm: cross-wave partials via LDS
        float pj[4];
#pragma unroll
        for (int j = 0; j < 4; j++) {
            float p = acc2[0][j] + acc2[1][j];
            p += __shfl_xor(p, 1); p += __shfl_xor(p, 2);
            p += __shfl_xor(p, 4); p += __shfl_xor(p, 8);
            pj[j] = p;
        }
        if (fr == 0) {
#pragma unroll
            for (int j = 0; j < 4; j++) pq[wv * 16 + kb * 4 + j] = pj[j];
        }
        __syncthreads();
        float mu[4];
#pragma unroll
        for (int j = 0; j < 4; j++)
            mu[j] = (pj[j] + pq[(wv ^ 1) * 16 + kb * 4 + j]) * (1.f / 64.f);
        float d[2][4], vj[4];
#pragma unroll
        for (int j = 0; j < 4; j++) {
            d[0][j] = acc2[0][j] - mu[j];
            d[1][j] = acc2[1][j] - mu[j];
            float v = d[0][j] * d[0][j] + d[1][j] * d[1][j];
            v += __shfl_xor(v, 1); v += __shfl_xor(v, 2);
            v += __shfl_xor(v, 4); v += __shfl_xor(v, 8);
            vj[j] = v;
        }
        if (fr == 0) {
#pragma unroll
            for (int j = 0; j < 4; j++) pq2[wv * 16 + kb * 4 + j] = vj[j];
        }
        __syncthreads();
        float gv[2], bev[2];
#pragma unroll
        for (int n2 = 0; n2 < 2; n2++) {
            gv[n2] = g[(nt0 + n2) * 16 + fr];
            bev[n2] = be[(nt0 + n2) * 16 + fr];
        }
#pragma unroll
        for (int j = 0; j < 4; j++) {
            float var = (vj[j] + pq2[(wv ^ 1) * 16 + kb * 4 + j]) * (1.f / 64.f);
            float is = 1.f / sqrtf(var + 1e-5f);
#pragma unroll
            for (int n2 = 0; n2 < 2; n2++)
                hs[kb * 4 + j][(nt0 + n2) * 16 + fr] = d[n2][j] * is * gv[n2] + bev[n2];
        }
        __syncthreads();
#pragma unroll
        for (int r = 0; r < 8; r++) {
            int rr = wv * 8 + r;
            feat[(long)idx[row0 + rr] * HIDD + l] = __float2bfloat16(hs[rr][l]);
        }
    } else {
        int flat = bx - 2500;
        int combo = flat & 3;
        int base = (flat >> 2) * CHUNKF;
        const int* tgt = (combo < 2 ? tgt_user : tgt_item) + (long)(combo & 1) * EEE;
        const int* emi = (combo < 2 ? emi_user : emi_item) + (long)(combo & 1) * EEE * 3;
        ushort4* sbuf = (ushort4*)pool;                 // 8192B
        int* lcnt  = (int*)(pool + 8192);
        int* lofs  = lcnt + 32;
        int* gbase = lofs + 33;
        int* lcur  = gbase + 32;
        int tid = threadIdx.x;
        if (tid < 32) { lcnt[tid] = 0; lcur[tid] = 0; }
        __syncthreads();
        ushort4 ent[8]; int bk[8];
#pragma unroll
        for (int ps = 0; ps < 8; ps++) {
            int i = base + ps * 128 + tid;
            if (i < EEE) {
                int t = tgt[i];
                ent[ps] = make_ushort4((unsigned short)emi[3 * i], (unsigned short)emi[3 * i + 1],
                                       (unsigned short)emi[3 * i + 2], (unsigned short)t);
                bk[ps] = t >> 8;
                atomicAdd(&lcnt[bk[ps]], 1);
            } else bk[ps] = -1;
        }
        __syncthreads();
        if (tid == 0) {
            int run = 0;
            for (int k = 0; k < 32; k++) { lofs[k] = run; run += lcnt[k]; }
            lofs[32] = run;
        }
        __syncthreads();
        if (tid < 32) gbase[tid] = atomicAdd(&cur32[combo * 32 + tid], lcnt[tid]);
        __syncthreads();
#pragma unroll
        for (int ps = 0; ps < 8; ps++) {
            if (bk[ps] >= 0) {
                int pos = lofs[bk[ps]] + atomicAdd(&lcur[bk[ps]], 1);
                sbuf[pos] = ent[ps];
            }
        }
        __syncthreads();
        int total = lofs[32];
        ushort4* dst = binbuf + (long)combo * EEE;
        for (int j = tid; j < total; j += 128) {
            ushort4 e = sbuf[j];
            int k = e.w >> 8;
            dst[gbase[k] + (j - lofs[k])] = e;
        }
    }
}

// ---------------- binB: LDS counting-sort per coarse bucket ----------------
#define BKCAP 7680
__global__ __launch_bounds__(256) void binB_kernel(
    const int* __restrict__ offs,
    const ushort4* __restrict__ binbuf, ushort4* __restrict__ nodes)
{
    int combo = blockIdx.y;
    int k = blockIdx.x;
    const int* of = offs + combo * (BBB + 1);
    int rbeg = of[k << 8], rend = of[(k + 1) << 8];
    int cnt = rend - rbeg;
    if (cnt > BKCAP) cnt = BKCAP;          // data-safe: 18 sigma above mean
    __shared__ ushort4 sbuf[BKCAP];        // 61440B
    __shared__ int lh[256];                // hist -> excl offsets
    __shared__ int part[256];              // scan scratch -> placement counters
    int tid = threadIdx.x;
    lh[tid] = 0;
    __syncthreads();
    const ushort4* src = binbuf + (long)combo * EEE + rbeg;
    for (int j = tid; j < cnt; j += 256)
        atomicAdd(&lh[src[j].w & 255], 1);
    __syncthreads();
    int myc = lh[tid];
    part[tid] = myc;
    __syncthreads();
    for (int d = 1; d < 256; d <<= 1) {
        int u = (tid >= d) ? part[tid - d] : 0;
        __syncthreads();
        part[tid] += u;
        __syncthreads();
    }
    int myofs = part[tid] - myc;           // exclusive prefix
    __syncthreads();
    lh[tid] = myofs;                       // lh := offsets
    part[tid] = 0;                         // part := placement counters
    __syncthreads();
    for (int j = tid; j < cnt; j += 256) {
        ushort4 e = src[j];
        int b = e.w & 255;
        int pos = lh[b] + atomicAdd(&part[b], 1);
        if (pos < BKCAP) sbuf[pos] = e;
    }
    __syncthreads();
    ushort4* dst = nodes + (long)combo * EEE + rbeg;
    for (int j = tid; j < cnt; j += 256) dst[j] = sbuf[j];
}

// ---------------- flash metapath: deferred rotation + packed f32 + online softmax + ELU ----------------
__global__ __launch_bounds__(256) void flash_mp(
    const __hip_bfloat16* __restrict__ feat, const ushort4* __restrict__ nodes,
    const int* __restrict__ offs, const float* __restrict__ r_vec,
    const float* __restrict__ attn_user, const float* __restrict__ attn_item,
    float* __restrict__ ret)
{
    int combo = blockIdx.y;
    int wid = threadIdx.x >> 6, lane = threadIdx.x & 63;
    int half = lane >> 5, p = lane & 31;
    int side = combo >> 1;
    const float* attn = (side == 0 ? attn_user : attn_item) + (combo & 1) * 64;
    const unsigned int* f2 = (const unsigned int*)feat;
    float2 rb = ((const float2*)r_vec)[p];
    float invn = 1.f / sqrtf(rb.x * rb.x + rb.y * rb.y);
    float rvx = rb.x * invn, rvy = rb.y * invn;
    if (side == 0) rvy = -rvy;
    float aRe = attn[2 * p], aIm = attn[2 * p + 1];
    f32x2 av  = { aRe * (1.f / 3.f), aIm * (1.f / 3.f) };
    f32x2 apv = { (rvx * aRe + rvy * aIm) * (1.f / 3.f),
                  (rvx * aIm - rvy * aRe) * (1.f / 3.f) };
    int t = blockIdx.x * 4 + wid;
    const int* of = offs + combo * (BBB + 1);
    int beg = of[t], end = of[t + 1];
    int n = end - beg;
    const ushort4* nd = nodes + (long)combo * EEE;

    float m = -3.4e38f, s = 0.f;
    f32x2 A02 = {0.f, 0.f}, A1 = {0.f, 0.f};

    unsigned int c0[4], c1[4], c2[4];
    ushort4 nq[4];
    if (n > 0) {
#pragma unroll
        for (int q = 0; q < 4; q++) {
            ushort4 a = nd[min(beg + 2 * q + half, EEE - 1)];
            c0[q] = f2[(int)a.x * 32 + p];
            c1[q] = f2[(int)a.y * 32 + p];
            c2[q] = f2[(int)a.z * 32 + p];
        }
#pragma unroll
        for (int q = 0; q < 4; q++)
            nq[q] = nd[min(beg + 8 + 2 * q + half, EEE - 1)];
    }
    for (int it = 0; it < n; it += 8) {
        f32x2 u1[4], v02[4];
        float e[4];
#pragma unroll
        for (int q = 0; q < 4; q++) {
            f32x2 u0 = bf2_to_f32x2(c0[q]);
            u1[q]    = bf2_to_f32x2(c1[q]);
            f32x2 u2 = bf2_to_f32x2(c2[q]);
            v02[q] = u0 + u2;
        }
        if (it + 8 < n) {
#pragma unroll
            for (int q = 0; q < 4; q++) {
                c0[q] = f2[(int)nq[q].x * 32 + p];
                c1[q] = f2[(int)nq[q].y * 32 + p];
                c2[q] = f2[(int)nq[q].z * 32 + p];
            }
#pragma unroll
            for (int q = 0; q < 4; q++)
                nq[q] = nd[min(beg + it + 16 + 2 * q + half, EEE - 1)];
        }
#pragma unroll
        for (int q = 0; q < 4; q++) {
            f32x2 tt = v02[q] * av + u1[q] * apv;
            float pa = tt.x + tt.y;
            pa += __shfl_xor(pa, 1);
            pa += __shfl_xor(pa, 2);
            e[q] = fmaxf(pa, 0.01f * pa);        // leaky_relu
        }
        if (it + 8 > n) {                        // tail chunk only (wave-uniform)
#pragma unroll
            for (int q = 0; q < 4; q++)
                if (it + 2 * q + half >= n) e[q] = -3.4e38f;
        }
        float mx = fmaxf(fmaxf(e[0], e[1]), fmaxf(e[2], e[3]));
        float mn = fmaxf(m, fmaxf(mx, __shfl_xor(mx, 32)));
        float alpha = __expf(m - mn);
        s *= alpha; A02 *= alpha; A1 *= alpha;
        float wl = 0.f;
#pragma unroll
        for (int q = 0; q < 4; q++) {
            float w = __expf(e[q] - mn);
            wl += w;
            A02 += v02[q] * w;
            A1  += u1[q] * w;
        }
        s += wl + __shfl_xor(wl, 32);
        m = mn;
    }
    float Sx = A02.x + __shfl_xor(A02.x, 32);
    float Sy = A02.y + __shfl_xor(A02.y, 32);
    float Tx = A1.x + __shfl_xor(A1.x, 32);
    float Ty = A1.y + __shfl_xor(A1.y, 32);
    float inv = (1.f / 3.f) / (s + 1e-9f);
    float vx = (Sx + rvx * Tx - rvy * Ty) * inv;
    float vy = (Sy + rvx * Ty + rvy * Tx) * inv;
    vx = vx > 0.f ? vx : __expf(vx) - 1.f;       // ELU
    vy = vy > 0.f ? vy : __expf(vy) - 1.f;
    if (half == 0)
        ((float2*)ret)[((long)combo * BBB + t) * 32 + p] = make_float2(vx, vy);
}

// ---------------- semantic score GEMM: s_acc[combo] = sum_b tanh(ret_b @ w1 + b1) @ w2 ----------------
__global__ __launch_bounds__(256) void sem_kernel(
    const float* __restrict__ ret,
    const float* __restrict__ su_w1, const float* __restrict__ su_b1, const float* __restrict__ su_w2,
    const float* __restrict__ si_w1, const float* __restrict__ si_b1, const float* __restrict__ si_w2,
    float* __restrict__ s_acc)
{
    int combo = blockIdx.y;
    int side = combo >> 1;
    const float* w1 = side ? si_w1 : su_w1;
    const float* b1 = side ? si_b1 : su_b1;
    const float* w2 = side ? si_w2 : su_w2;
    __shared__ float vs[64][68];
    __shared__ float w1s[64][128];
    int tid = threadIdx.x;
    int rowbase = blockIdx.x * 64;
    const float4* r4 = (const float4*)ret;
    for (int li = tid; li < 1024; li += 256) {
        int r = li >> 4, c4 = li & 15;
        float4 v = r4[((long)combo * BBB + rowbase + r) * 16 + c4];
        *(float4*)&vs[r][c4 * 4] = v;
    }
    const float4* w14 = (const float4*)w1;
    for (int li = tid; li < 2048; li += 256) {
        float4 v = w14[li];
        *(float4*)&w1s[li >> 5][(li & 31) * 4] = v;
    }
    __syncthreads();
    int ct = tid & 15, rt = tid >> 4;
    float acc[4][8];
#pragma unroll
    for (int cc = 0; cc < 8; cc++) {
        float b = b1[8 * ct + cc];
#pragma unroll
        for (int j = 0; j < 4; j++) acc[j][cc] = b;
    }
    for (int k = 0; k < 64; k += 4) {
        float4 xv[4];
#pragma unroll
        for (int j = 0; j < 4; j++) xv[j] = *(const float4*)&vs[4 * rt + j][k];
#pragma unroll
        for (int kk = 0; kk < 4; kk++) {
            float4 wv0 = *(const float4*)&w1s[k + kk][8 * ct];
            float4 wv1 = *(const float4*)&w1s[k + kk][8 * ct + 4];
#pragma unroll
            for (int j = 0; j < 4; j++) {
                float xx = kk == 0 ? xv[j].x : kk == 1 ? xv[j].y : kk == 2 ? xv[j].z : xv[j].w;
                acc[j][0] = fmaf(xx, wv0.x, acc[j][0]);
                acc[j][1] = fmaf(xx, wv0.y, acc[j][1]);
                acc[j][2] = fmaf(xx, wv0.z, acc[j][2]);
                acc[j][3] = fmaf(xx, wv0.w, acc[j][3]);
                acc[j][4] = fmaf(xx, wv1.x, acc[j][4]);
                acc[j][5] = fmaf(xx, wv1.y, acc[j][5]);
                acc[j][6] = fmaf(xx, wv1.z, acc[j][6]);
                acc[j][7] = fmaf(xx, wv1.w, acc[j][7]);
            }
        }
    }
    float tot = 0.f;
#pragma unroll
    for (int cc = 0; cc < 8; cc++) {
        float w2v = w2[8 * ct + cc];
#pragma unroll
        for (int j = 0; j < 4; j++) tot += fast_tanh(acc[j][cc]) * w2v;
    }
    for (int off = 32; off; off >>= 1) tot += __shfl_xor(tot, off);
    __shared__ float red[4];
    int lane = tid & 63, wid = tid >> 6;
    if (lane == 0) red[wid] = tot;
    __syncthreads();
    if (tid == 0) atomicAdd(&s_acc[combo], red[0] + red[1] + red[2] + red[3]);
}

// ---------------- final product MLP + softmax (beta inline, GEMM-tiled) ----------------
__global__ __launch_bounds__(256) void final_kernel(
    const float* __restrict__ ret, const float* __restrict__ s_acc,
    const float* __restrict__ cw1, const float* __restrict__ cb1, const float* __restrict__ cw2,
    float* __restrict__ outp)
{
    float s0 = s_acc[0] * (1.f / BBB), s1 = s_acc[1] * (1.f / BBB);
    float s2 = s_acc[2] * (1.f / BBB), s3 = s_acc[3] * (1.f / BBB);
    float mu = fmaxf(s0, s1);
    float e0 = __expf(s0 - mu), e1 = __expf(s1 - mu);
    float bu0 = e0 / (e0 + e1), bu1 = e1 / (e0 + e1);
    float mi = fmaxf(s2, s3);
    float f0 = __expf(s2 - mi), f1 = __expf(s3 - mi);
    float bi0 = f0 / (f0 + f1), bi1 = f1 / (f0 + f1);

    __shared__ float xsld[64][68];
    __shared__ float w1s[64][128];
    int tid = threadIdx.x;
    int rowbase = blockIdx.x * 64;
    const float4* r4 = (const float4*)ret;
    for (int li = tid; li < 1024; li += 256) {
        int r = li >> 4, c4 = li & 15;
        float4 a = r4[((long)0 * BBB + rowbase + r) * 16 + c4];
        float4 b = r4[((long)1 * BBB + rowbase + r) * 16 + c4];
        float4 cc = r4[((long)2 * BBB + rowbase + r) * 16 + c4];
        float4 d = r4[((long)3 * BBB + rowbase + r) * 16 + c4];
        float4 xv;
        xv.x = (bu0 * a.x + bu1 * b.x) * (bi0 * cc.x + bi1 * d.x);
        xv.y = (bu0 * a.y + bu1 * b.y) * (bi0 * cc.y + bi1 * d.y);
        xv.z = (bu0 * a.z + bu1 * b.z) * (bi0 * cc.z + bi1 * d.z);
        xv.w = (bu0 * a.w + bu1 * b.w) * (bi0 * cc.w + bi1 * d.w);
        *(float4*)&xsld[r][c4 * 4] = xv;
    }
    const float4* w14 = (const float4*)cw1;
    for (int li = tid; li < 2048; li += 256) {
        float4 v = w14[li];
        *(float4*)&w1s[li >> 5][(li & 31) * 4] = v;
    }
    __syncthreads();
    int ct = tid & 15, rt = tid >> 4;
    float acc[4][8];
#pragma unroll
    for (int cc = 0; cc < 8; cc++) {
        float b = cb1[8 * ct + cc];
#pragma unroll
        for (int j = 0; j < 4; j++) acc[j][cc] = b;
    }
    for (int k = 0; k < 64; k += 4) {
        float4 xv[4];
#pragma unroll
        for (int j = 0; j < 4; j++) xv[j] = *(const float4*)&xsld[4 * rt + j][k];
#pragma unroll
        for (int kk = 0; kk < 4; kk++) {
            float4 wv0 = *(const float4*)&w1s[k + kk][8 * ct];
            float4 wv1 = *(const float4*)&w1s[k + kk][8 * ct + 4];
#pragma unroll
            for (int j = 0; j < 4; j++) {
                float xx = kk == 0 ? xv[j].x : kk == 1 ? xv[j].y : kk == 2 ? xv[j].z : xv[j].w;
                acc[j][0] = fmaf(xx, wv0.x, acc[j][0]);
                acc[j][1] = fmaf(xx, wv0.y, acc[j][1]);
                acc[j][2] = fmaf(xx, wv0.z, acc[j][2]);
                acc[j][3] = fmaf(xx, wv0.w, acc[j][3]);
                acc[j][4] = fmaf(xx, wv1.x, acc[j][4]);
                acc[j][5] = fmaf(xx, wv1.y, acc[j][5]);
                acc[j][6] = fmaf(xx, wv1.z, acc[j][6]);
                acc[j][7] = fmaf(xx, wv1.w, acc[j][7]);
            }
        }
    }
    float pp0[4], pp1[4];
#pragma unroll
    for (int j = 0; j < 4; j++) { pp0[j] = 0.f; pp1[j] = 0.f; }
#pragma unroll
    for (int cc = 0; cc < 8; cc++) {
        int col = 8 * ct + cc;
        float c0 = cw2[col * 2], c1 = cw2[col * 2 + 1];
#pragma unroll
        for (int j = 0; j < 4; j++) {
            float h = fmaxf(acc[j][cc], 0.f);
            pp0[j] = fmaf(h, c0, pp0[j]);
            pp1[j] = fmaf(h, c1, pp1[j]);
        }
    }
    __syncthreads();
    float2* red = (float2*)xsld;
#pragma unroll
    for (int j = 0; j < 4; j++)
        red[(4 * rt + j) * 16 + ct] = make_float2(pp0[j], pp1[j]);
    __syncthreads();
    if (tid < 64) {
        float q0 = 0.f, q1 = 0.f;
        for (int i = 0; i < 16; i++) {
            float2 e = red[tid * 16 + i];
            q0 += e.x; q1 += e.y;
        }
        float mx = fmaxf(q0, q1);
        float a0 = __expf(q0 - mx), a1 = __expf(q1 - mx);
        float dn = a0 + a1;
        outp[(rowbase + tid) * 2] = a0 / dn;
        outp[(rowbase + tid) * 2 + 1] = a1 / dn;
    }
}

extern "C" void kernel_launch(void* const* d_in, const int* in_sizes, int n_in,
                              void* d_out, int out_size, void* d_ws, size_t ws_size,
                              hipStream_t stream)
{
    const float* feats0 = (const float*)d_in[0];
    const float* feats1 = (const float*)d_in[1];
    const float* t0_pw = (const float*)d_in[2];
    const float* t0_pb = (const float*)d_in[3];
    const float* t0_w2 = (const float*)d_in[4];
    const float* t0_b2 = (const float*)d_in[5];
    const float* t0_g  = (const float*)d_in[6];
    const float* t0_be = (const float*)d_in[7];
    const float* t1_pw = (const float*)d_in[8];
    const float* t1_pb = (const float*)d_in[9];
    const float* t1_w2 = (const float*)d_in[10];
    const float* t1_b2 = (const float*)d_in[11];
    const float* t1_g  = (const float*)d_in[12];
    const float* t1_be = (const float*)d_in[13];
    const float* r_vec = (const float*)d_in[14];
    const float* attn_user = (const float*)d_in[15];
    const float* attn_item = (const float*)d_in[16];
    const float* su_w1 = (const float*)d_in[17];
    const float* su_b1 = (const float*)d_in[18];
    const float* su_w2 = (const float*)d_in[19];
    const float* si_w1 = (const float*)d_in[20];
    const float* si_b1 = (const float*)d_in[21];
    const float* si_w2 = (const float*)d_in[22];
    const float* cw1 = (const float*)d_in[23];
    const float* cb1 = (const float*)d_in[24];
    const float* cw2 = (const float*)d_in[25];
    const int* idx0 = (const int*)d_in[26];
    const int* idx1 = (const int*)d_in[27];
    const int* emi_user = (const int*)d_in[28];
    const int* tgt_user = (const int*)d_in[29];
    const int* emi_item = (const int*)d_in[30];
    const int* tgt_item = (const int*)d_in[31];
    float* outp = (float*)d_out;

    // workspace layout (256B aligned)
    char* ws = (char*)d_ws;
    __hip_bfloat16* feat = (__hip_bfloat16*)(ws + 0);   // 5,120,000
    int*     cnt    = (int*)(ws + 5120000);             // 131,072
    int*     cur32  = (int*)(ws + 5382144);             // 512
    int*     offs   = (int*)(ws + 5382656);             // 131,088 -> pad 131,328
    float*   s_acc  = (float*)(ws + 5513984);           // 256
    ushort4* binbuf = (ushort4*)(ws + 5514240);         // 6,400,000
    ushort4* nodes  = (ushort4*)(ws + 11914240);        // 6,400,000
    float*   ret_buf= (float*)(ws + 18314240);          // 8,388,608
    __bf16*  wprep  = (__bf16*)(ws + 26702848);         // 262,144  (end ~27.0 MB)
    // w2prep (32KB) aliases the start of `nodes`: written by prep_hist, read by tower
    // (tower_binA), then overwritten by binB which runs strictly after. binA writes
    // only binbuf, so the concurrent tower reads are race-free.
    __bf16*  w2prep = (__bf16*)(ws + 11914240);

    hipMemsetAsync(cnt, 0, 4 * BBB * sizeof(int), stream);

    prep_hist<<<16 + 4 * ((EEE + 255) / 256), 256, 0, stream>>>(
        t0_pw, t1_pw, t0_w2, t1_w2, wprep, w2prep, tgt_user, tgt_item, cnt);

    scan_kernel<<<4, 256, 0, stream>>>(cnt, offs, cur32, s_acc);

    tower_binA<<<2500 + 4 * ((EEE + CHUNKF - 1) / CHUNKF), 128, 0, stream>>>(
        feats0, feats1, wprep, w2prep, t0_pb, t1_pb,
        t0_b2, t1_b2, t0_g, t1_g, t0_be, t1_be, idx0, idx1, feat,
        tgt_user, tgt_item, emi_user, emi_item, cur32, binbuf);

    binB_kernel<<<dim3(32, 4), 256, 0, stream>>>(offs, binbuf, nodes);

    flash_mp<<<dim3(BBB / 4, 4), 256, 0, stream>>>(feat, nodes, offs, r_vec,
                                                   attn_user, attn_item, ret_buf);

    sem_kernel<<<dim3(BBB / 64, 4), 256, 0, stream>>>(ret_buf, su_w1, su_b1, su_w2,
                                                      si_w1, si_b1, si_w2, s_acc);
    final_kernel<<<BBB / 64, 256, 0, stream>>>(ret_buf, s_acc, cw1, cb1, cw2, outp);
}

// Round 9
// 292.533 us; speedup vs baseline: 1.3124x; 1.1207x over previous
//
#include <hip/hip_runtime.h>
#include <hip/hip_bf16.h>
#include <math.h>

// MAGNN link prediction forward — fp32 compute; feat table stored bf16.
// Tower: per-wave MFMA GEMM (split-bf16 hi/lo, 3 MFMAs ~ fp32 accuracy), 2-wave col-split,
//        sched_barrier-pinned register prefetch (r8: compiler sank prefetch, VGPR=48).
// CSR: coarse-only histogram; binB LDS counting-sort derives fine offsets and writes offs[]
//      (r8: global fine hist + 4-block scan kernel were redundant — deleted).
// Flash: deferred-rotation packed-f32 online softmax. Sem: standalone GEMM-tiled kernel.
#define NN0 20000
#define NN1 20000
#define NTOT 40000
#define FF0 512
#define HIDD 64
#define EEE 200000
#define BBB 8192
#define AVV 128
#define CHH 128

typedef __bf16 bf16x8 __attribute__((ext_vector_type(8)));
typedef __bf16 bf16x4 __attribute__((ext_vector_type(4)));
typedef float f32x4 __attribute__((ext_vector_type(4)));
typedef float f32x2 __attribute__((ext_vector_type(2)));

__device__ __forceinline__ float fast_tanh(float x) {
    float e2 = __expf(2.f * x);
    return 1.f - 2.f / (e2 + 1.f);
}

__device__ __forceinline__ f32x2 bf2_to_f32x2(unsigned int c) {
    f32x2 r;
    r.x = __uint_as_float(c << 16);
    r.y = __uint_as_float(c & 0xffff0000u);
    return r;
}

// 32-lane exclusive prefix over padded coarse counters (counter stride 32 ints = 128B
// to avoid same-line atomic serialization). Caller guards tid<32 (wave-0 lanes).
__device__ __forceinline__ void coarse_prefix(const int* __restrict__ cnt32p, int combo, int tid,
                                              int& cv, int& excl) {
    cv = cnt32p[(combo * 32 + tid) * 32];
    int pre = cv;
#pragma unroll
    for (int d = 1; d < 32; d <<= 1) {
        int o = __shfl_up(pre, d);
        if (tid >= d) pre += o;
    }
    excl = pre - cv;
}

// ---------------- fused: weight prep (blocks 0..15) + coarse target histogram (rest) -----------
#define HCHUNK 1024
__global__ __launch_bounds__(256) void prep_hist(
    const float* __restrict__ pw0, const float* __restrict__ pw1,
    const float* __restrict__ w20, const float* __restrict__ w21,
    __bf16* __restrict__ wprep, __bf16* __restrict__ w2prep,
    const int* __restrict__ tgt_user, const int* __restrict__ tgt_item,
    int* __restrict__ cnt32p)
{
    __shared__ int ch[32];
    int bx = blockIdx.x;
    if (bx < 16) {
        int tw = bx & 1, seg = bx >> 1;
        const float* w = tw ? pw1 : pw0;
        __bf16* base = wprep + tw * 65536;
        for (int idx = seg * 4096 + threadIdx.x; idx < (seg + 1) * 4096; idx += 256) {
            int k = idx >> 6, n = idx & 63;
            float v = w[idx];
            __bf16 hi = (__bf16)v;
            __bf16 lo = (__bf16)(v - (float)hi);
            int ks = k >> 5, kb = (k >> 3) & 3, j = k & 7;
            int nt = n >> 4, fr = n & 15;
            int lane = kb * 16 + fr;
            int off = ((ks * 4 + nt) * 64 + lane) * 8 + j;
            base[off] = hi;
            base[32768 + off] = lo;
        }
        const float* w2 = tw ? w21 : w20;
        __bf16* base2 = w2prep + tw * 8192;
        for (int idx = seg * 512 + threadIdx.x; idx < (seg + 1) * 512; idx += 256) {
            int k = idx >> 6, n = idx & 63;
            float v = w2[idx];
            __bf16 hi = (__bf16)v;
            __bf16 lo = (__bf16)(v - (float)hi);
            int ks = k >> 5, kb = (k >> 3) & 3, j = k & 7;
            int nt = n >> 4, fr = n & 15;
            int lane = kb * 16 + fr;
            int off = ((ks * 4 + nt) * 64 + lane) * 8 + j;
            base2[off] = hi;
            base2[4096 + off] = lo;
        }
    } else {
        int flat = bx - 16;                    // 0..783
        int combo = flat & 3, blk = flat >> 2; // blk 0..195
        const int* tgt = (combo < 2 ? tgt_user : tgt_item) + (long)(combo & 1) * EEE;
        int tid = threadIdx.x;
        if (tid < 32) ch[tid] = 0;
        __syncthreads();
        int base = blk * HCHUNK;
#pragma unroll
        for (int q = 0; q < 4; q++) {
            int i = base + q * 256 + tid;
            if (i < EEE) atomicAdd(&ch[tgt[i] >> 8], 1);
        }
        __syncthreads();
        if (tid < 32 && ch[tid]) atomicAdd(&cnt32p[(combo * 32 + tid) * 32], ch[tid]);
    }
}

// ---------------- fused: tower MFMA (blocks 0..2499) + binA coarse binning (rest) ----------------
#define CHUNKF 1024
__global__ __launch_bounds__(128) void tower_binA(
    const float* __restrict__ x0, const float* __restrict__ x1,
    const __bf16* __restrict__ wprep, const __bf16* __restrict__ w2prep,
    const float* __restrict__ pb0, const float* __restrict__ pb1,
    const float* __restrict__ b20, const float* __restrict__ b21,
    const float* __restrict__ g0, const float* __restrict__ g1,
    const float* __restrict__ be0, const float* __restrict__ be1,
    const int* __restrict__ idxa, const int* __restrict__ idxb,
    __hip_bfloat16* __restrict__ feat,
    const int* __restrict__ tgt_user, const int* __restrict__ tgt_item,
    const int* __restrict__ emi_user, const int* __restrict__ emi_item,
    const int* __restrict__ cnt32p, int* __restrict__ cur32cnt,
    ushort4* __restrict__ binbuf)
{
    __shared__ __align__(16) char pool[8960];
    int bx = blockIdx.x;
    if (bx < 2500) {
        int tile = bx >> 1, tw = bx & 1;
        const float* x  = tw ? x1 : x0;
        const float* pb = tw ? pb1 : pb0;
        const float* b2 = tw ? b21 : b20;
        const float* g  = tw ? g1 : g0;
        const float* be = tw ? be1 : be0;
        const int* idx  = tw ? idxb : idxa;
        float (*hs)[68] = (float(*)[68])pool;          // 4352B
        float* pq  = (float*)(pool + 4352);            // [2][16]
        float* pq2 = (float*)(pool + 4480);            // [2][16]

        int wv = threadIdx.x >> 6;                     // wave 0/1: cols 32wv..32wv+31
        int l = threadIdx.x & 63;
        int fr = l & 15, kb = l >> 4;
        int nt0 = 2 * wv;
        int row0 = tile * 16;
        const float* xp = x + (long)(row0 + fr) * FF0 + kb * 8;
        const __bf16* bp = wprep + tw * 65536;

        f32x4 acc[2];
#pragma unroll
        for (int n2 = 0; n2 < 2; n2++) acc[n2] = (f32x4){0.f, 0.f, 0.f, 0.f};

        float4 a0c, a1c, a0n, a1n;
        bf16x8 bhc[2], blc[2], bhn[2], bln[2];

        a0c = *(const float4*)xp;
        a1c = *(const float4*)(xp + 4);
#pragma unroll
        for (int n2 = 0; n2 < 2; n2++) {
            bhc[n2] = *(const bf16x8*)(bp + ((nt0 + n2) * 64 + l) * 8);
            blc[n2] = *(const bf16x8*)(bp + 32768 + ((nt0 + n2) * 64 + l) * 8);
        }

#pragma unroll 2
        for (int ks = 0; ks < 16; ks++) {
            if (ks + 1 < 16) {
                a0n = *(const float4*)(xp + (ks + 1) * 32);
                a1n = *(const float4*)(xp + (ks + 1) * 32 + 4);
#pragma unroll
                for (int n2 = 0; n2 < 2; n2++) {
                    bhn[n2] = *(const bf16x8*)(bp + (((ks + 1) * 4 + nt0 + n2) * 64 + l) * 8);
                    bln[n2] = *(const bf16x8*)(bp + 32768 + (((ks + 1) * 4 + nt0 + n2) * 64 + l) * 8);
                }
            }
            // pin prefetch issue BEFORE the convert+MFMA body (compiler sank it in r4/r5)
            __builtin_amdgcn_sched_barrier(0);
            float av[8] = {a0c.x, a0c.y, a0c.z, a0c.w, a1c.x, a1c.y, a1c.z, a1c.w};
            bf16x8 ah, al;
#pragma unroll
            for (int j = 0; j < 8; j++) {
                __bf16 h = (__bf16)av[j];
                ah[j] = h;
                al[j] = (__bf16)(av[j] - (float)h);
            }
#pragma unroll
            for (int n2 = 0; n2 < 2; n2++) {
                acc[n2] = __builtin_amdgcn_mfma_f32_16x16x32_bf16(ah, bhc[n2], acc[n2], 0, 0, 0);
                acc[n2] = __builtin_amdgcn_mfma_f32_16x16x32_bf16(al, bhc[n2], acc[n2], 0, 0, 0);
                acc[n2] = __builtin_amdgcn_mfma_f32_16x16x32_bf16(ah, blc[n2], acc[n2], 0, 0, 0);
            }
            a0c = a0n; a1c = a1n;
#pragma unroll
            for (int n2 = 0; n2 < 2; n2++) { bhc[n2] = bhn[n2]; blc[n2] = bln[n2]; }
        }

        // epilogue 1: z = acc + pb; h = gelu(z) -> hs; acc2 = z + b2
        float pbv[2], b2v[2];
#pragma unroll
        for (int n2 = 0; n2 < 2; n2++) {
            pbv[n2] = pb[(nt0 + n2) * 16 + fr];
            b2v[n2] = b2[(nt0 + n2) * 16 + fr];
        }
        f32x4 acc2[2];
#pragma unroll
        for (int n2 = 0; n2 < 2; n2++) {
#pragma unroll
            for (int j = 0; j < 4; j++) {
                float z = acc[n2][j] + pbv[n2];
                float h = 0.5f * z * (1.f + erff(z * 0.70710678118654752f));
                hs[kb * 4 + j][(nt0 + n2) * 16 + fr] = h;
                acc2[n2][j] = z + b2v[n2];
            }
        }
        __syncthreads();

        // GEMM2 (MFMA): y = h@w2 + b2 + z
        const __bf16* w2p = w2prep + tw * 8192;
#pragma unroll
        for (int ks = 0; ks < 2; ks++) {
            float4 h0 = *(const float4*)&hs[fr][ks * 32 + kb * 8];
            float4 h1 = *(const float4*)&hs[fr][ks * 32 + kb * 8 + 4];
            float hv[8] = {h0.x, h0.y, h0.z, h0.w, h1.x, h1.y, h1.z, h1.w};
            bf16x8 ah, al;
#pragma unroll
            for (int j = 0; j < 8; j++) {
                __bf16 h = (__bf16)hv[j];
                ah[j] = h;
                al[j] = (__bf16)(hv[j] - (float)h);
            }
#pragma unroll
            for (int n2 = 0; n2 < 2; n2++) {
                bf16x8 bh2 = *(const bf16x8*)(w2p + ((ks * 4 + nt0 + n2) * 64 + l) * 8);
                bf16x8 bl2 = *(const bf16x8*)(w2p + 4096 + ((ks * 4 + nt0 + n2) * 64 + l) * 8);
                acc2[n2] = __builtin_amdgcn_mfma_f32_16x16x32_bf16(ah, bh2, acc2[n2], 0, 0, 0);
                acc2[n2] = __builtin_amdgcn_mfma_f32_16x16x32_bf16(al, bh2, acc2[n2], 0, 0, 0);
                acc2[n2] = __builtin_amdgcn_mfma_f32_16x16x32_bf16(ah, bl2, acc2[n2], 0, 0, 0);
            }
        }

        // LayerNorm: cross-wave partials via LDS
        float pj[4];
#pragma unroll
        for (int j = 0; j < 4; j++) {
            float p = acc2[0][j] + acc2[1][j];
            p += __shfl_xor(p, 1); p += __shfl_xor(p, 2);
            p += __shfl_xor(p, 4); p += __shfl_xor(p, 8);
            pj[j] = p;
        }
        if (fr == 0) {
#pragma unroll
            for (int j = 0; j < 4; j++) pq[wv * 16 + kb * 4 + j] = pj[j];
        }
        __syncthreads();
        float mu[4];
#pragma unroll
        for (int j = 0; j < 4; j++)
            mu[j] = (pj[j] + pq[(wv ^ 1) * 16 + kb * 4 + j]) * (1.f / 64.f);
        float d[2][4], vj[4];
#pragma unroll
        for (int j = 0; j < 4; j++) {
            d[0][j] = acc2[0][j] - mu[j];
            d[1][j] = acc2[1][j] - mu[j];
            float v = d[0][j] * d[0][j] + d[1][j] * d[1][j];
            v += __shfl_xor(v, 1); v += __shfl_xor(v, 2);
            v += __shfl_xor(v, 4); v += __shfl_xor(v, 8);
            vj[j] = v;
        }
        if (fr == 0) {
#pragma unroll
            for (int j = 0; j < 4; j++) pq2[wv * 16 + kb * 4 + j] = vj[j];
        }
        __syncthreads();
        float gv[2], bev[2];
#pragma unroll
        for (int n2 = 0; n2 < 2; n2++) {
            gv[n2] = g[(nt0 + n2) * 16 + fr];
            bev[n2] = be[(nt0 + n2) * 16 + fr];
        }
#pragma unroll
        for (int j = 0; j < 4; j++) {
            float var = (vj[j] + pq2[(wv ^ 1) * 16 + kb * 4 + j]) * (1.f / 64.f);
            float is = 1.f / sqrtf(var + 1e-5f);
#pragma unroll
            for (int n2 = 0; n2 < 2; n2++)
                hs[kb * 4 + j][(nt0 + n2) * 16 + fr] = d[n2][j] * is * gv[n2] + bev[n2];
        }
        __syncthreads();
#pragma unroll
        for (int r = 0; r < 8; r++) {
            int rr = wv * 8 + r;
            feat[(long)idx[row0 + rr] * HIDD + l] = __float2bfloat16(hs[rr][l]);
        }
    } else {
        int flat = bx - 2500;
        int combo = flat & 3;
        int base = (flat >> 2) * CHUNKF;
        const int* tgt = (combo < 2 ? tgt_user : tgt_item) + (long)(combo & 1) * EEE;
        const int* emi = (combo < 2 ? emi_user : emi_item) + (long)(combo & 1) * EEE * 3;
        ushort4* sbuf = (ushort4*)pool;                 // 8192B
        int* lcnt  = (int*)(pool + 8192);
        int* lofs  = lcnt + 32;
        int* gbase = lofs + 33;
        int* lcur  = gbase + 32;
        int tid = threadIdx.x;
        if (tid < 32) { lcnt[tid] = 0; lcur[tid] = 0; }
        __syncthreads();
        ushort4 ent[8]; int bk[8];
#pragma unroll
        for (int ps = 0; ps < 8; ps++) {
            int i = base + ps * 128 + tid;
            if (i < EEE) {
                int t = tgt[i];
                ent[ps] = make_ushort4((unsigned short)emi[3 * i], (unsigned short)emi[3 * i + 1],
                                       (unsigned short)emi[3 * i + 2], (unsigned short)t);
                bk[ps] = t >> 8;
                atomicAdd(&lcnt[bk[ps]], 1);
            } else bk[ps] = -1;
        }
        __syncthreads();
        if (tid == 0) {
            int run = 0;
            for (int k = 0; k < 32; k++) { lofs[k] = run; run += lcnt[k]; }
            lofs[32] = run;
        }
        __syncthreads();
        if (tid < 32) {
            int cv, excl;
            coarse_prefix(cnt32p, combo, tid, cv, excl);
            gbase[tid] = excl + atomicAdd(&cur32cnt[combo * 32 + tid], lcnt[tid]);
        }
        __syncthreads();
#pragma unroll
        for (int ps = 0; ps < 8; ps++) {
            if (bk[ps] >= 0) {
                int pos = lofs[bk[ps]] + atomicAdd(&lcur[bk[ps]], 1);
                sbuf[pos] = ent[ps];
            }
        }
        __syncthreads();
        int total = lofs[32];
        ushort4* dst = binbuf + (long)combo * EEE;
        for (int j = tid; j < total; j += 128) {
            ushort4 e = sbuf[j];
            int k = e.w >> 8;
            dst[gbase[k] + (j - lofs[k])] = e;
        }
    }
}

// ---------------- binB: LDS counting-sort per coarse bucket; also writes CSR offs ----------------
#define BKCAP 7680
__global__ __launch_bounds__(256) void binB_kernel(
    const int* __restrict__ cnt32p, int* __restrict__ offs,
    const ushort4* __restrict__ binbuf, ushort4* __restrict__ nodes)
{
    int combo = blockIdx.y;
    int k = blockIdx.x;
    __shared__ ushort4 sbuf[BKCAP];        // 61440B
    __shared__ int lh[256];                // hist -> excl offsets
    __shared__ int part[256];              // scan scratch -> placement counters
    __shared__ int cex[32], ccn[32];
    int tid = threadIdx.x;
    if (tid < 32) {
        int cv, excl;
        coarse_prefix(cnt32p, combo, tid, cv, excl);
        cex[tid] = excl;
        ccn[tid] = cv;
    }
    lh[tid] = 0;
    __syncthreads();
    int rbeg = cex[k];
    int cnt = ccn[k];
    if (cnt > BKCAP) cnt = BKCAP;          // data-safe: 18 sigma above mean
    const ushort4* src = binbuf + (long)combo * EEE + rbeg;
    for (int j = tid; j < cnt; j += 256)
        atomicAdd(&lh[src[j].w & 255], 1);
    __syncthreads();
    int myc = lh[tid];
    part[tid] = myc;
    __syncthreads();
    for (int d = 1; d < 256; d <<= 1) {
        int u = (tid >= d) ? part[tid - d] : 0;
        __syncthreads();
        part[tid] += u;
        __syncthreads();
    }
    int myofs = part[tid] - myc;           // fine exclusive prefix within bucket
    // write CSR offsets for this bucket (replaces the deleted scan kernel)
    offs[combo * (BBB + 1) + (k << 8) + tid] = rbeg + myofs;
    if (k == 31 && tid == 0) offs[combo * (BBB + 1) + BBB] = EEE;
    __syncthreads();
    lh[tid] = myofs;                       // lh := offsets
    part[tid] = 0;                         // part := placement counters
    __syncthreads();
    for (int j = tid; j < cnt; j += 256) {
        ushort4 e = src[j];
        int b = e.w & 255;
        int pos = lh[b] + atomicAdd(&part[b], 1);
        if (pos < BKCAP) sbuf[pos] = e;
    }
    __syncthreads();
    ushort4* dst = nodes + (long)combo * EEE + rbeg;
    for (int j = tid; j < cnt; j += 256) dst[j] = sbuf[j];
}

// ---------------- flash metapath: deferred rotation + packed f32 + online softmax + ELU ----------------
__global__ __launch_bounds__(256) void flash_mp(
    const __hip_bfloat16* __restrict__ feat, const ushort4* __restrict__ nodes,
    const int* __restrict__ offs, const float* __restrict__ r_vec,
    const float* __restrict__ attn_user, const float* __restrict__ attn_item,
    float* __restrict__ ret)
{
    int combo = blockIdx.y;
    int wid = threadIdx.x >> 6, lane = threadIdx.x & 63;
    int half = lane >> 5, p = lane & 31;
    int side = combo >> 1;
    const float* attn = (side == 0 ? attn_user : attn_item) + (combo & 1) * 64;
    const unsigned int* f2 = (const unsigned int*)feat;
    float2 rb = ((const float2*)r_vec)[p];
    float invn = 1.f / sqrtf(rb.x * rb.x + rb.y * rb.y);
    float rvx = rb.x * invn, rvy = rb.y * invn;
    if (side == 0) rvy = -rvy;
    float aRe = attn[2 * p], aIm = attn[2 * p + 1];
    f32x2 av  = { aRe * (1.f / 3.f), aIm * (1.f / 3.f) };
    f32x2 apv = { (rvx * aRe + rvy * aIm) * (1.f / 3.f),
                  (rvx * aIm - rvy * aRe) * (1.f / 3.f) };
    int t = blockIdx.x * 4 + wid;
    const int* of = offs + combo * (BBB + 1);
    int beg = of[t], end = of[t + 1];
    int n = end - beg;
    const ushort4* nd = nodes + (long)combo * EEE;

    float m = -3.4e38f, s = 0.f;
    f32x2 A02 = {0.f, 0.f}, A1 = {0.f, 0.f};

    unsigned int c0[4], c1[4], c2[4];
    ushort4 nq[4];
    if (n > 0) {
#pragma unroll
        for (int q = 0; q < 4; q++) {
            ushort4 a = nd[min(beg + 2 * q + half, EEE - 1)];
            c0[q] = f2[(int)a.x * 32 + p];
            c1[q] = f2[(int)a.y * 32 + p];
            c2[q] = f2[(int)a.z * 32 + p];
        }
#pragma unroll
        for (int q = 0; q < 4; q++)
            nq[q] = nd[min(beg + 8 + 2 * q + half, EEE - 1)];
    }
    for (int it = 0; it < n; it += 8) {
        f32x2 u1[4], v02[4];
        float e[4];
#pragma unroll
        for (int q = 0; q < 4; q++) {
            f32x2 u0 = bf2_to_f32x2(c0[q]);
            u1[q]    = bf2_to_f32x2(c1[q]);
            f32x2 u2 = bf2_to_f32x2(c2[q]);
            v02[q] = u0 + u2;
        }
        if (it + 8 < n) {
#pragma unroll
            for (int q = 0; q < 4; q++) {
                c0[q] = f2[(int)nq[q].x * 32 + p];
                c1[q] = f2[(int)nq[q].y * 32 + p];
                c2[q] = f2[(int)nq[q].z * 32 + p];
            }
#pragma unroll
            for (int q = 0; q < 4; q++)
                nq[q] = nd[min(beg + it + 16 + 2 * q + half, EEE - 1)];
        }
#pragma unroll
        for (int q = 0; q < 4; q++) {
            f32x2 tt = v02[q] * av + u1[q] * apv;
            float pa = tt.x + tt.y;
            pa += __shfl_xor(pa, 1);
            pa += __shfl_xor(pa, 2);
            e[q] = fmaxf(pa, 0.01f * pa);        // leaky_relu
        }
        if (it + 8 > n) {                        // tail chunk only (wave-uniform)
#pragma unroll
            for (int q = 0; q < 4; q++)
                if (it + 2 * q + half >= n) e[q] = -3.4e38f;
        }
        float mx = fmaxf(fmaxf(e[0], e[1]), fmaxf(e[2], e[3]));
        float mn = fmaxf(m, fmaxf(mx, __shfl_xor(mx, 32)));
        float alpha = __expf(m - mn);
        s *= alpha; A02 *= alpha; A1 *= alpha;
        float wl = 0.f;
#pragma unroll
        for (int q = 0; q < 4; q++) {
            float w = __expf(e[q] - mn);
            wl += w;
            A02 += v02[q] * w;
            A1  += u1[q] * w;
        }
        s += wl + __shfl_xor(wl, 32);
        m = mn;
    }
    float Sx = A02.x + __shfl_xor(A02.x, 32);
    float Sy = A02.y + __shfl_xor(A02.y, 32);
    float Tx = A1.x + __shfl_xor(A1.x, 32);
    float Ty = A1.y + __shfl_xor(A1.y, 32);
    float inv = (1.f / 3.f) / (s + 1e-9f);
    float vx = (Sx + rvx * Tx - rvy * Ty) * inv;
    float vy = (Sy + rvx * Ty + rvy * Tx) * inv;
    vx = vx > 0.f ? vx : __expf(vx) - 1.f;       // ELU
    vy = vy > 0.f ? vy : __expf(vy) - 1.f;
    if (half == 0)
        ((float2*)ret)[((long)combo * BBB + t) * 32 + p] = make_float2(vx, vy);
}

// ---------------- semantic score GEMM: s_acc[combo] = sum_b tanh(ret_b @ w1 + b1) @ w2 ----------------
__global__ __launch_bounds__(256) void sem_kernel(
    const float* __restrict__ ret,
    const float* __restrict__ su_w1, const float* __restrict__ su_b1, const float* __restrict__ su_w2,
    const float* __restrict__ si_w1, const float* __restrict__ si_b1, const float* __restrict__ si_w2,
    float* __restrict__ s_acc)
{
    int combo = blockIdx.y;
    int side = combo >> 1;
    const float* w1 = side ? si_w1 : su_w1;
    const float* b1 = side ? si_b1 : su_b1;
    const float* w2 = side ? si_w2 : su_w2;
    __shared__ float vs[64][68];
    __shared__ float w1s[64][128];
    int tid = threadIdx.x;
    int rowbase = blockIdx.x * 64;
    const float4* r4 = (const float4*)ret;
    for (int li = tid; li < 1024; li += 256) {
        int r = li >> 4, c4 = li & 15;
        float4 v = r4[((long)combo * BBB + rowbase + r) * 16 + c4];
        *(float4*)&vs[r][c4 * 4] = v;
    }
    const float4* w14 = (const float4*)w1;
    for (int li = tid; li < 2048; li += 256) {
        float4 v = w14[li];
        *(float4*)&w1s[li >> 5][(li & 31) * 4] = v;
    }
    __syncthreads();
    int ct = tid & 15, rt = tid >> 4;
    float acc[4][8];
#pragma unroll
    for (int cc = 0; cc < 8; cc++) {
        float b = b1[8 * ct + cc];
#pragma unroll
        for (int j = 0; j < 4; j++) acc[j][cc] = b;
    }
    for (int k = 0; k < 64; k += 4) {
        float4 xv[4];
#pragma unroll
        for (int j = 0; j < 4; j++) xv[j] = *(const float4*)&vs[4 * rt + j][k];
#pragma unroll
        for (int kk = 0; kk < 4; kk++) {
            float4 wv0 = *(const float4*)&w1s[k + kk][8 * ct];
            float4 wv1 = *(const float4*)&w1s[k + kk][8 * ct + 4];
#pragma unroll
            for (int j = 0; j < 4; j++) {
                float xx = kk == 0 ? xv[j].x : kk == 1 ? xv[j].y : kk == 2 ? xv[j].z : xv[j].w;
                acc[j][0] = fmaf(xx, wv0.x, acc[j][0]);
                acc[j][1] = fmaf(xx, wv0.y, acc[j][1]);
                acc[j][2] = fmaf(xx, wv0.z, acc[j][2]);
                acc[j][3] = fmaf(xx, wv0.w, acc[j][3]);
                acc[j][4] = fmaf(xx, wv1.x, acc[j][4]);
                acc[j][5] = fmaf(xx, wv1.y, acc[j][5]);
                acc[j][6] = fmaf(xx, wv1.z, acc[j][6]);
                acc[j][7] = fmaf(xx, wv1.w, acc[j][7]);
            }
        }
    }
    float tot = 0.f;
#pragma unroll
    for (int cc = 0; cc < 8; cc++) {
        float w2v = w2[8 * ct + cc];
#pragma unroll
        for (int j = 0; j < 4; j++) tot += fast_tanh(acc[j][cc]) * w2v;
    }
    for (int off = 32; off; off >>= 1) tot += __shfl_xor(tot, off);
    __shared__ float red[4];
    int lane = tid & 63, wid = tid >> 6;
    if (lane == 0) red[wid] = tot;
    __syncthreads();
    if (tid == 0) atomicAdd(&s_acc[combo], red[0] + red[1] + red[2] + red[3]);
}

// ---------------- final product MLP + softmax (beta inline, GEMM-tiled) ----------------
__global__ __launch_bounds__(256) void final_kernel(
    const float* __restrict__ ret, const float* __restrict__ s_acc,
    const float* __restrict__ cw1, const float* __restrict__ cb1, const float* __restrict__ cw2,
    float* __restrict__ outp)
{
    float s0 = s_acc[0] * (1.f / BBB), s1 = s_acc[1] * (1.f / BBB);
    float s2 = s_acc[2] * (1.f / BBB), s3 = s_acc[3] * (1.f / BBB);
    float mu = fmaxf(s0, s1);
    float e0 = __expf(s0 - mu), e1 = __expf(s1 - mu);
    float bu0 = e0 / (e0 + e1), bu1 = e1 / (e0 + e1);
    float mi = fmaxf(s2, s3);
    float f0 = __expf(s2 - mi), f1 = __expf(s3 - mi);
    float bi0 = f0 / (f0 + f1), bi1 = f1 / (f0 + f1);

    __shared__ float xsld[64][68];
    __shared__ float w1s[64][128];
    int tid = threadIdx.x;
    int rowbase = blockIdx.x * 64;
    const float4* r4 = (const float4*)ret;
    for (int li = tid; li < 1024; li += 256) {
        int r = li >> 4, c4 = li & 15;
        float4 a = r4[((long)0 * BBB + rowbase + r) * 16 + c4];
        float4 b = r4[((long)1 * BBB + rowbase + r) * 16 + c4];
        float4 cc = r4[((long)2 * BBB + rowbase + r) * 16 + c4];
        float4 d = r4[((long)3 * BBB + rowbase + r) * 16 + c4];
        float4 xv;
        xv.x = (bu0 * a.x + bu1 * b.x) * (bi0 * cc.x + bi1 * d.x);
        xv.y = (bu0 * a.y + bu1 * b.y) * (bi0 * cc.y + bi1 * d.y);
        xv.z = (bu0 * a.z + bu1 * b.z) * (bi0 * cc.z + bi1 * d.z);
        xv.w = (bu0 * a.w + bu1 * b.w) * (bi0 * cc.w + bi1 * d.w);
        *(float4*)&xsld[r][c4 * 4] = xv;
    }
    const float4* w14 = (const float4*)cw1;
    for (int li = tid; li < 2048; li += 256) {
        float4 v = w14[li];
        *(float4*)&w1s[li >> 5][(li & 31) * 4] = v;
    }
    __syncthreads();
    int ct = tid & 15, rt = tid >> 4;
    float acc[4][8];
#pragma unroll
    for (int cc = 0; cc < 8; cc++) {
        float b = cb1[8 * ct + cc];
#pragma unroll
        for (int j = 0; j < 4; j++) acc[j][cc] = b;
    }
    for (int k = 0; k < 64; k += 4) {
        float4 xv[4];
#pragma unroll
        for (int j = 0; j < 4; j++) xv[j] = *(const float4*)&xsld[4 * rt + j][k];
#pragma unroll
        for (int kk = 0; kk < 4; kk++) {
            float4 wv0 = *(const float4*)&w1s[k + kk][8 * ct];
            float4 wv1 = *(const float4*)&w1s[k + kk][8 * ct + 4];
#pragma unroll
            for (int j = 0; j < 4; j++) {
                float xx = kk == 0 ? xv[j].x : kk == 1 ? xv[j].y : kk == 2 ? xv[j].z : xv[j].w;
                acc[j][0] = fmaf(xx, wv0.x, acc[j][0]);
                acc[j][1] = fmaf(xx, wv0.y, acc[j][1]);
                acc[j][2] = fmaf(xx, wv0.z, acc[j][2]);
                acc[j][3] = fmaf(xx, wv0.w, acc[j][3]);
                acc[j][4] = fmaf(xx, wv1.x, acc[j][4]);
                acc[j][5] = fmaf(xx, wv1.y, acc[j][5]);
                acc[j][6] = fmaf(xx, wv1.z, acc[j][6]);
                acc[j][7] = fmaf(xx, wv1.w, acc[j][7]);
            }
        }
    }
    float pp0[4], pp1[4];
#pragma unroll
    for (int j = 0; j < 4; j++) { pp0[j] = 0.f; pp1[j] = 0.f; }
#pragma unroll
    for (int cc = 0; cc < 8; cc++) {
        int col = 8 * ct + cc;
        float c0 = cw2[col * 2], c1 = cw2[col * 2 + 1];
#pragma unroll
        for (int j = 0; j < 4; j++) {
            float h = fmaxf(acc[j][cc], 0.f);
            pp0[j] = fmaf(h, c0, pp0[j]);
            pp1[j] = fmaf(h, c1, pp1[j]);
        }
    }
    __syncthreads();
    float2* red = (float2*)xsld;
#pragma unroll
    for (int j = 0; j < 4; j++)
        red[(4 * rt + j) * 16 + ct] = make_float2(pp0[j], pp1[j]);
    __syncthreads();
    if (tid < 64) {
        float q0 = 0.f, q1 = 0.f;
        for (int i = 0; i < 16; i++) {
            float2 e = red[tid * 16 + i];
            q0 += e.x; q1 += e.y;
        }
        float mx = fmaxf(q0, q1);
        float a0 = __expf(q0 - mx), a1 = __expf(q1 - mx);
        float dn = a0 + a1;
        outp[(rowbase + tid) * 2] = a0 / dn;
        outp[(rowbase + tid) * 2 + 1] = a1 / dn;
    }
}

extern "C" void kernel_launch(void* const* d_in, const int* in_sizes, int n_in,
                              void* d_out, int out_size, void* d_ws, size_t ws_size,
                              hipStream_t stream)
{
    const float* feats0 = (const float*)d_in[0];
    const float* feats1 = (const float*)d_in[1];
    const float* t0_pw = (const float*)d_in[2];
    const float* t0_pb = (const float*)d_in[3];
    const float* t0_w2 = (const float*)d_in[4];
    const float* t0_b2 = (const float*)d_in[5];
    const float* t0_g  = (const float*)d_in[6];
    const float* t0_be = (const float*)d_in[7];
    const float* t1_pw = (const float*)d_in[8];
    const float* t1_pb = (const float*)d_in[9];
    const float* t1_w2 = (const float*)d_in[10];
    const float* t1_b2 = (const float*)d_in[11];
    const float* t1_g  = (const float*)d_in[12];
    const float* t1_be = (const float*)d_in[13];
    const float* r_vec = (const float*)d_in[14];
    const float* attn_user = (const float*)d_in[15];
    const float* attn_item = (const float*)d_in[16];
    const float* su_w1 = (const float*)d_in[17];
    const float* su_b1 = (const float*)d_in[18];
    const float* su_w2 = (const float*)d_in[19];
    const float* si_w1 = (const float*)d_in[20];
    const float* si_b1 = (const float*)d_in[21];
    const float* si_w2 = (const float*)d_in[22];
    const float* cw1 = (const float*)d_in[23];
    const float* cb1 = (const float*)d_in[24];
    const float* cw2 = (const float*)d_in[25];
    const int* idx0 = (const int*)d_in[26];
    const int* idx1 = (const int*)d_in[27];
    const int* emi_user = (const int*)d_in[28];
    const int* tgt_user = (const int*)d_in[29];
    const int* emi_item = (const int*)d_in[30];
    const int* tgt_item = (const int*)d_in[31];
    float* outp = (float*)d_out;

    // workspace layout (256B aligned)
    char* ws = (char*)d_ws;
    __hip_bfloat16* feat = (__hip_bfloat16*)(ws + 0);   // 5,120,000
    int*     cnt32p  = (int*)(ws + 5120000);            // 16,384 (128 counters, 128B stride)
    int*     cur32cnt= (int*)(ws + 5136384);            // 512
    float*   s_acc   = (float*)(ws + 5136896);          // 256  (memset covers all three: 17,152B)
    int*     offs    = (int*)(ws + 5137408);            // 131,088 -> pad
    ushort4* binbuf  = (ushort4*)(ws + 5268736);        // 6,400,000
    ushort4* nodes   = (ushort4*)(ws + 11668736);       // 6,400,000
    float*   ret_buf = (float*)(ws + 18068736);         // 8,388,608
    __bf16*  wprep   = (__bf16*)(ws + 26457344);        // 262,144  (end ~26.7 MB)
    // w2prep (32KB) aliases the start of `nodes`: written by prep_hist, read by tower
    // (tower_binA), then overwritten by binB which runs strictly after. binA writes
    // only binbuf, so the concurrent tower reads are race-free.
    __bf16*  w2prep  = (__bf16*)(ws + 11668736);

    hipMemsetAsync(cnt32p, 0, 16384 + 512 + 256, stream);

    prep_hist<<<16 + 4 * ((EEE + HCHUNK - 1) / HCHUNK), 256, 0, stream>>>(
        t0_pw, t1_pw, t0_w2, t1_w2, wprep, w2prep, tgt_user, tgt_item, cnt32p);

    tower_binA<<<2500 + 4 * ((EEE + CHUNKF - 1) / CHUNKF), 128, 0, stream>>>(
        feats0, feats1, wprep, w2prep, t0_pb, t1_pb,
        t0_b2, t1_b2, t0_g, t1_g, t0_be, t1_be, idx0, idx1, feat,
        tgt_user, tgt_item, emi_user, emi_item, cnt32p, cur32cnt, binbuf);

    binB_kernel<<<dim3(32, 4), 256, 0, stream>>>(cnt32p, offs, binbuf, nodes);

    flash_mp<<<dim3(BBB / 4, 4), 256, 0, stream>>>(feat, nodes, offs, r_vec,
                                                   attn_user, attn_item, ret_buf);

    sem_kernel<<<dim3(BBB / 64, 4), 256, 0, stream>>>(ret_buf, su_w1, su_b1, su_w2,
                                                      si_w1, si_b1, si_w2, s_acc);
    final_kernel<<<BBB / 64, 256, 0, stream>>>(ret_buf, s_acc, cw1, cb1, cw2, outp);
}

// Round 10
// 281.272 us; speedup vs baseline: 1.3649x; 1.0400x over previous
//
#include <hip/hip_runtime.h>
#include <hip/hip_bf16.h>
#include <math.h>

// MAGNN link prediction forward — fp32 compute; feat table stored bf16.
// Tower: per-wave MFMA GEMM (split-bf16 hi/lo, 3 MFMAs ~ fp32 accuracy), 2-wave col-split.
// CSR: coarse-only histogram; binB LDS counting-sort (512 thr) derives fine offsets + offs[].
// prep: inverse-mapped coalesced writes (r9: scattered 2B stores were RMW-serialized).
// Flash: deferred-rotation packed-f32 online softmax. Sem: standalone GEMM-tiled kernel.
#define NN0 20000
#define NN1 20000
#define NTOT 40000
#define FF0 512
#define HIDD 64
#define EEE 200000
#define BBB 8192
#define AVV 128
#define CHH 128

typedef __bf16 bf16x8 __attribute__((ext_vector_type(8)));
typedef __bf16 bf16x4 __attribute__((ext_vector_type(4)));
typedef float f32x4 __attribute__((ext_vector_type(4)));
typedef float f32x2 __attribute__((ext_vector_type(2)));

__device__ __forceinline__ float fast_tanh(float x) {
    float e2 = __expf(2.f * x);
    return 1.f - 2.f / (e2 + 1.f);
}

__device__ __forceinline__ f32x2 bf2_to_f32x2(unsigned int c) {
    f32x2 r;
    r.x = __uint_as_float(c << 16);
    r.y = __uint_as_float(c & 0xffff0000u);
    return r;
}

// 32-lane exclusive prefix over padded coarse counters (counter stride 32 ints = 128B
// to avoid same-line atomic serialization). Caller guards tid<32 (wave-0 lanes).
__device__ __forceinline__ void coarse_prefix(const int* __restrict__ cnt32p, int combo, int tid,
                                              int& cv, int& excl) {
    cv = cnt32p[(combo * 32 + tid) * 32];
    int pre = cv;
#pragma unroll
    for (int d = 1; d < 32; d <<= 1) {
        int o = __shfl_up(pre, d);
        if (tid >= d) pre += o;
    }
    excl = pre - cv;
}

// ---------------- fused: weight prep (blocks 0..35, coalesced) + coarse histogram (rest) -------
// prep inverse map: output chunk c2 -> ksnt=c2>>6, lane=c2&63; k=ks*32+(lane>>4)*8+j,
// n=nt*16+(lane&15). Thread does 8 strided loads, writes hi+lo bf16x8 (16B coalesced stores).
#define HCHUNK 1024
__global__ __launch_bounds__(256) void prep_hist(
    const float* __restrict__ pw0, const float* __restrict__ pw1,
    const float* __restrict__ w20, const float* __restrict__ w21,
    __bf16* __restrict__ wprep, __bf16* __restrict__ w2prep,
    const int* __restrict__ tgt_user, const int* __restrict__ tgt_item,
    int* __restrict__ cnt32p)
{
    __shared__ int ch[32];
    int bx = blockIdx.x;
    if (bx < 32) {
        int tw = bx & 1;
        int c2 = (bx >> 1) * 256 + threadIdx.x;        // 0..4095
        const float* w = tw ? pw1 : pw0;
        int ksnt = c2 >> 6, lane = c2 & 63;
        int ks = ksnt >> 2, nt = ksnt & 3;
        int kb = lane >> 4, fr = lane & 15;
        const float* src = w + (ks * 32 + kb * 8) * 64 + nt * 16 + fr;
        bf16x8 hi, lo;
#pragma unroll
        for (int j = 0; j < 8; j++) {
            float v = src[j * 64];
            __bf16 h = (__bf16)v;
            hi[j] = h;
            lo[j] = (__bf16)(v - (float)h);
        }
        __bf16* base = wprep + tw * 65536;
        *(bf16x8*)(base + c2 * 8) = hi;
        *(bf16x8*)(base + 32768 + c2 * 8) = lo;
    } else if (bx < 36) {
        int tw = bx & 1;
        int c2 = ((bx - 32) >> 1) * 256 + threadIdx.x; // 0..511
        const float* w2 = tw ? w21 : w20;
        int ksnt = c2 >> 6, lane = c2 & 63;            // ks 0..1
        int ks = ksnt >> 2, nt = ksnt & 3;
        int kb = lane >> 4, fr = lane & 15;
        const float* src = w2 + (ks * 32 + kb * 8) * 64 + nt * 16 + fr;
        bf16x8 hi, lo;
#pragma unroll
        for (int j = 0; j < 8; j++) {
            float v = src[j * 64];
            __bf16 h = (__bf16)v;
            hi[j] = h;
            lo[j] = (__bf16)(v - (float)h);
        }
        __bf16* base2 = w2prep + tw * 8192;
        *(bf16x8*)(base2 + c2 * 8) = hi;
        *(bf16x8*)(base2 + 4096 + c2 * 8) = lo;
    } else {
        int flat = bx - 36;                    // 0..783
        int combo = flat & 3, blk = flat >> 2; // blk 0..195
        const int* tgt = (combo < 2 ? tgt_user : tgt_item) + (long)(combo & 1) * EEE;
        int tid = threadIdx.x;
        if (tid < 32) ch[tid] = 0;
        __syncthreads();
        int base = blk * HCHUNK;
#pragma unroll
        for (int q = 0; q < 4; q++) {
            int i = base + q * 256 + tid;
            if (i < EEE) atomicAdd(&ch[tgt[i] >> 8], 1);
        }
        __syncthreads();
        if (tid < 32 && ch[tid]) atomicAdd(&cnt32p[(combo * 32 + tid) * 32], ch[tid]);
    }
}

// ---------------- fused: tower MFMA (blocks 0..2499) + binA coarse binning (rest) ----------------
#define CHUNKF 1024
__global__ __launch_bounds__(128) void tower_binA(
    const float* __restrict__ x0, const float* __restrict__ x1,
    const __bf16* __restrict__ wprep, const __bf16* __restrict__ w2prep,
    const float* __restrict__ pb0, const float* __restrict__ pb1,
    const float* __restrict__ b20, const float* __restrict__ b21,
    const float* __restrict__ g0, const float* __restrict__ g1,
    const float* __restrict__ be0, const float* __restrict__ be1,
    const int* __restrict__ idxa, const int* __restrict__ idxb,
    __hip_bfloat16* __restrict__ feat,
    const int* __restrict__ tgt_user, const int* __restrict__ tgt_item,
    const int* __restrict__ emi_user, const int* __restrict__ emi_item,
    const int* __restrict__ cnt32p, int* __restrict__ cur32cnt,
    ushort4* __restrict__ binbuf)
{
    __shared__ __align__(16) char pool[8960];
    int bx = blockIdx.x;
    if (bx < 2500) {
        int tile = bx >> 1, tw = bx & 1;
        const float* x  = tw ? x1 : x0;
        const float* pb = tw ? pb1 : pb0;
        const float* b2 = tw ? b21 : b20;
        const float* g  = tw ? g1 : g0;
        const float* be = tw ? be1 : be0;
        const int* idx  = tw ? idxb : idxa;
        float (*hs)[68] = (float(*)[68])pool;          // 4352B
        float* pq  = (float*)(pool + 4352);            // [2][16]
        float* pq2 = (float*)(pool + 4480);            // [2][16]

        int wv = threadIdx.x >> 6;                     // wave 0/1: cols 32wv..32wv+31
        int l = threadIdx.x & 63;
        int fr = l & 15, kb = l >> 4;
        int nt0 = 2 * wv;
        int row0 = tile * 16;
        const float* xp = x + (long)(row0 + fr) * FF0 + kb * 8;
        const __bf16* bp = wprep + tw * 65536;

        f32x4 acc[2];
#pragma unroll
        for (int n2 = 0; n2 < 2; n2++) acc[n2] = (f32x4){0.f, 0.f, 0.f, 0.f};

        float4 a0c, a1c, a0n, a1n;
        bf16x8 bhc[2], blc[2], bhn[2], bln[2];

        a0c = *(const float4*)xp;
        a1c = *(const float4*)(xp + 4);
#pragma unroll
        for (int n2 = 0; n2 < 2; n2++) {
            bhc[n2] = *(const bf16x8*)(bp + ((nt0 + n2) * 64 + l) * 8);
            blc[n2] = *(const bf16x8*)(bp + 32768 + ((nt0 + n2) * 64 + l) * 8);
        }

#pragma unroll 2
        for (int ks = 0; ks < 16; ks++) {
            if (ks + 1 < 16) {
                a0n = *(const float4*)(xp + (ks + 1) * 32);
                a1n = *(const float4*)(xp + (ks + 1) * 32 + 4);
#pragma unroll
                for (int n2 = 0; n2 < 2; n2++) {
                    bhn[n2] = *(const bf16x8*)(bp + (((ks + 1) * 4 + nt0 + n2) * 64 + l) * 8);
                    bln[n2] = *(const bf16x8*)(bp + 32768 + (((ks + 1) * 4 + nt0 + n2) * 64 + l) * 8);
                }
            }
            float av[8] = {a0c.x, a0c.y, a0c.z, a0c.w, a1c.x, a1c.y, a1c.z, a1c.w};
            bf16x8 ah, al;
#pragma unroll
            for (int j = 0; j < 8; j++) {
                __bf16 h = (__bf16)av[j];
                ah[j] = h;
                al[j] = (__bf16)(av[j] - (float)h);
            }
#pragma unroll
            for (int n2 = 0; n2 < 2; n2++) {
                acc[n2] = __builtin_amdgcn_mfma_f32_16x16x32_bf16(ah, bhc[n2], acc[n2], 0, 0, 0);
                acc[n2] = __builtin_amdgcn_mfma_f32_16x16x32_bf16(al, bhc[n2], acc[n2], 0, 0, 0);
                acc[n2] = __builtin_amdgcn_mfma_f32_16x16x32_bf16(ah, blc[n2], acc[n2], 0, 0, 0);
            }
            a0c = a0n; a1c = a1n;
#pragma unroll
            for (int n2 = 0; n2 < 2; n2++) { bhc[n2] = bhn[n2]; blc[n2] = bln[n2]; }
        }

        // epilogue 1: z = acc + pb; h = gelu(z) -> hs; acc2 = z + b2
        float pbv[2], b2v[2];
#pragma unroll
        for (int n2 = 0; n2 < 2; n2++) {
            pbv[n2] = pb[(nt0 + n2) * 16 + fr];
            b2v[n2] = b2[(nt0 + n2) * 16 + fr];
        }
        f32x4 acc2[2];
#pragma unroll
        for (int n2 = 0; n2 < 2; n2++) {
#pragma unroll
            for (int j = 0; j < 4; j++) {
                float z = acc[n2][j] + pbv[n2];
                float h = 0.5f * z * (1.f + erff(z * 0.70710678118654752f));
                hs[kb * 4 + j][(nt0 + n2) * 16 + fr] = h;
                acc2[n2][j] = z + b2v[n2];
            }
        }
        __syncthreads();

        // GEMM2 (MFMA): y = h@w2 + b2 + z
        const __bf16* w2p = w2prep + tw * 8192;
#pragma unroll
        for (int ks = 0; ks < 2; ks++) {
            float4 h0 = *(const float4*)&hs[fr][ks * 32 + kb * 8];
            float4 h1 = *(const float4*)&hs[fr][ks * 32 + kb * 8 + 4];
            float hv[8] = {h0.x, h0.y, h0.z, h0.w, h1.x, h1.y, h1.z, h1.w};
            bf16x8 ah, al;
#pragma unroll
            for (int j = 0; j < 8; j++) {
                __bf16 h = (__bf16)hv[j];
                ah[j] = h;
                al[j] = (__bf16)(hv[j] - (float)h);
            }
#pragma unroll
            for (int n2 = 0; n2 < 2; n2++) {
                bf16x8 bh2 = *(const bf16x8*)(w2p + ((ks * 4 + nt0 + n2) * 64 + l) * 8);
                bf16x8 bl2 = *(const bf16x8*)(w2p + 4096 + ((ks * 4 + nt0 + n2) * 64 + l) * 8);
                acc2[n2] = __builtin_amdgcn_mfma_f32_16x16x32_bf16(ah, bh2, acc2[n2], 0, 0, 0);
                acc2[n2] = __builtin_amdgcn_mfma_f32_16x16x32_bf16(al, bh2, acc2[n2], 0, 0, 0);
                acc2[n2] = __builtin_amdgcn_mfma_f32_16x16x32_bf16(ah, bl2, acc2[n2], 0, 0, 0);
            }
        }

        // LayerNorm: cross-wave partials via LDS
        float pj[4];
#pragma unroll
        for (int j = 0; j < 4; j++) {
            float p = acc2[0][j] + acc2[1][j];
            p += __shfl_xor(p, 1); p += __shfl_xor(p, 2);
            p += __shfl_xor(p, 4); p += __shfl_xor(p, 8);
            pj[j] = p;
        }
        if (fr == 0) {
#pragma unroll
            for (int j = 0; j < 4; j++) pq[wv * 16 + kb * 4 + j] = pj[j];
        }
        __syncthreads();
        float mu[4];
#pragma unroll
        for (int j = 0; j < 4; j++)
            mu[j] = (pj[j] + pq[(wv ^ 1) * 16 + kb * 4 + j]) * (1.f / 64.f);
        float d[2][4], vj[4];
#pragma unroll
        for (int j = 0; j < 4; j++) {
            d[0][j] = acc2[0][j] - mu[j];
            d[1][j] = acc2[1][j] - mu[j];
            float v = d[0][j] * d[0][j] + d[1][j] * d[1][j];
            v += __shfl_xor(v, 1); v += __shfl_xor(v, 2);
            v += __shfl_xor(v, 4); v += __shfl_xor(v, 8);
            vj[j] = v;
        }
        if (fr == 0) {
#pragma unroll
            for (int j = 0; j < 4; j++) pq2[wv * 16 + kb * 4 + j] = vj[j];
        }
        __syncthreads();
        float gv[2], bev[2];
#pragma unroll
        for (int n2 = 0; n2 < 2; n2++) {
            gv[n2] = g[(nt0 + n2) * 16 + fr];
            bev[n2] = be[(nt0 + n2) * 16 + fr];
        }
#pragma unroll
        for (int j = 0; j < 4; j++) {
            float var = (vj[j] + pq2[(wv ^ 1) * 16 + kb * 4 + j]) * (1.f / 64.f);
            float is = 1.f / sqrtf(var + 1e-5f);
#pragma unroll
            for (int n2 = 0; n2 < 2; n2++)
                hs[kb * 4 + j][(nt0 + n2) * 16 + fr] = d[n2][j] * is * gv[n2] + bev[n2];
        }
        __syncthreads();
#pragma unroll
        for (int r = 0; r < 8; r++) {
            int rr = wv * 8 + r;
            feat[(long)idx[row0 + rr] * HIDD + l] = __float2bfloat16(hs[rr][l]);
        }
    } else {
        int flat = bx - 2500;
        int combo = flat & 3;
        int base = (flat >> 2) * CHUNKF;
        const int* tgt = (combo < 2 ? tgt_user : tgt_item) + (long)(combo & 1) * EEE;
        const int* emi = (combo < 2 ? emi_user : emi_item) + (long)(combo & 1) * EEE * 3;
        ushort4* sbuf = (ushort4*)pool;                 // 8192B
        int* lcnt  = (int*)(pool + 8192);
        int* lofs  = lcnt + 32;
        int* gbase = lofs + 33;
        int* lcur  = gbase + 32;
        int tid = threadIdx.x;
        if (tid < 32) { lcnt[tid] = 0; lcur[tid] = 0; }
        __syncthreads();
        ushort4 ent[8]; int bk[8];
#pragma unroll
        for (int ps = 0; ps < 8; ps++) {
            int i = base + ps * 128 + tid;
            if (i < EEE) {
                int t = tgt[i];
                ent[ps] = make_ushort4((unsigned short)emi[3 * i], (unsigned short)emi[3 * i + 1],
                                       (unsigned short)emi[3 * i + 2], (unsigned short)t);
                bk[ps] = t >> 8;
                atomicAdd(&lcnt[bk[ps]], 1);
            } else bk[ps] = -1;
        }
        __syncthreads();
        if (tid == 0) {
            int run = 0;
            for (int k = 0; k < 32; k++) { lofs[k] = run; run += lcnt[k]; }
            lofs[32] = run;
        }
        __syncthreads();
        if (tid < 32) {
            int cv, excl;
            coarse_prefix(cnt32p, combo, tid, cv, excl);
            gbase[tid] = excl + atomicAdd(&cur32cnt[combo * 32 + tid], lcnt[tid]);
        }
        __syncthreads();
#pragma unroll
        for (int ps = 0; ps < 8; ps++) {
            if (bk[ps] >= 0) {
                int pos = lofs[bk[ps]] + atomicAdd(&lcur[bk[ps]], 1);
                sbuf[pos] = ent[ps];
            }
        }
        __syncthreads();
        int total = lofs[32];
        ushort4* dst = binbuf + (long)combo * EEE;
        for (int j = tid; j < total; j += 128) {
            ushort4 e = sbuf[j];
            int k = e.w >> 8;
            dst[gbase[k] + (j - lofs[k])] = e;
        }
    }
}

// ---------------- binB: LDS counting-sort per coarse bucket (512 thr); writes CSR offs ----------
#define BKCAP 7680
__global__ __launch_bounds__(512) void binB_kernel(
    const int* __restrict__ cnt32p, int* __restrict__ offs,
    const ushort4* __restrict__ binbuf, ushort4* __restrict__ nodes)
{
    int combo = blockIdx.y;
    int k = blockIdx.x;
    __shared__ ushort4 sbuf[BKCAP];        // 61440B
    __shared__ int lh[256];                // hist -> excl offsets
    __shared__ int part[256];              // scan scratch -> placement counters
    __shared__ int cex[32], ccn[32];
    int tid = threadIdx.x;
    if (tid < 32) {
        int cv, excl;
        coarse_prefix(cnt32p, combo, tid, cv, excl);
        cex[tid] = excl;
        ccn[tid] = cv;
    }
    if (tid < 256) lh[tid] = 0;
    __syncthreads();
    int rbeg = cex[k];
    int cnt = ccn[k];
    if (cnt > BKCAP) cnt = BKCAP;          // data-safe: 18 sigma above mean
    const ushort4* src = binbuf + (long)combo * EEE + rbeg;
    for (int j = tid; j < cnt; j += 512)
        atomicAdd(&lh[src[j].w & 255], 1);
    __syncthreads();
    int myc = 0;
    if (tid < 256) { myc = lh[tid]; part[tid] = myc; }
    __syncthreads();
    for (int d = 1; d < 256; d <<= 1) {
        int u = (tid < 256 && tid >= d) ? part[tid - d] : 0;
        __syncthreads();
        if (tid < 256) part[tid] += u;
        __syncthreads();
    }
    int myofs = 0;
    if (tid < 256) {
        myofs = part[tid] - myc;           // fine exclusive prefix within bucket
        offs[combo * (BBB + 1) + (k << 8) + tid] = rbeg + myofs;
    }
    if (k == 31 && tid == 0) offs[combo * (BBB + 1) + BBB] = EEE;
    __syncthreads();
    if (tid < 256) { lh[tid] = myofs; part[tid] = 0; }
    __syncthreads();
    for (int j = tid; j < cnt; j += 512) {
        ushort4 e = src[j];
        int b = e.w & 255;
        int pos = lh[b] + atomicAdd(&part[b], 1);
        if (pos < BKCAP) sbuf[pos] = e;
    }
    __syncthreads();
    ushort4* dst = nodes + (long)combo * EEE + rbeg;
    for (int j = tid; j < cnt; j += 512) dst[j] = sbuf[j];
}

// ---------------- flash metapath: deferred rotation + packed f32 + online softmax + ELU ----------------
__global__ __launch_bounds__(256) void flash_mp(
    const __hip_bfloat16* __restrict__ feat, const ushort4* __restrict__ nodes,
    const int* __restrict__ offs, const float* __restrict__ r_vec,
    const float* __restrict__ attn_user, const float* __restrict__ attn_item,
    float* __restrict__ ret)
{
    int combo = blockIdx.y;
    int wid = threadIdx.x >> 6, lane = threadIdx.x & 63;
    int half = lane >> 5, p = lane & 31;
    int side = combo >> 1;
    const float* attn = (side == 0 ? attn_user : attn_item) + (combo & 1) * 64;
    const unsigned int* f2 = (const unsigned int*)feat;
    float2 rb = ((const float2*)r_vec)[p];
    float invn = 1.f / sqrtf(rb.x * rb.x + rb.y * rb.y);
    float rvx = rb.x * invn, rvy = rb.y * invn;
    if (side == 0) rvy = -rvy;
    float aRe = attn[2 * p], aIm = attn[2 * p + 1];
    f32x2 av  = { aRe * (1.f / 3.f), aIm * (1.f / 3.f) };
    f32x2 apv = { (rvx * aRe + rvy * aIm) * (1.f / 3.f),
                  (rvx * aIm - rvy * aRe) * (1.f / 3.f) };
    int t = blockIdx.x * 4 + wid;
    const int* of = offs + combo * (BBB + 1);
    int beg = of[t], end = of[t + 1];
    int n = end - beg;
    const ushort4* nd = nodes + (long)combo * EEE;

    float m = -3.4e38f, s = 0.f;
    f32x2 A02 = {0.f, 0.f}, A1 = {0.f, 0.f};

    unsigned int c0[4], c1[4], c2[4];
    ushort4 nq[4];
    if (n > 0) {
#pragma unroll
        for (int q = 0; q < 4; q++) {
            ushort4 a = nd[min(beg + 2 * q + half, EEE - 1)];
            c0[q] = f2[(int)a.x * 32 + p];
            c1[q] = f2[(int)a.y * 32 + p];
            c2[q] = f2[(int)a.z * 32 + p];
        }
#pragma unroll
        for (int q = 0; q < 4; q++)
            nq[q] = nd[min(beg + 8 + 2 * q + half, EEE - 1)];
    }
    for (int it = 0; it < n; it += 8) {
        f32x2 u1[4], v02[4];
        float e[4];
#pragma unroll
        for (int q = 0; q < 4; q++) {
            f32x2 u0 = bf2_to_f32x2(c0[q]);
            u1[q]    = bf2_to_f32x2(c1[q]);
            f32x2 u2 = bf2_to_f32x2(c2[q]);
            v02[q] = u0 + u2;
        }
        if (it + 8 < n) {
#pragma unroll
            for (int q = 0; q < 4; q++) {
                c0[q] = f2[(int)nq[q].x * 32 + p];
                c1[q] = f2[(int)nq[q].y * 32 + p];
                c2[q] = f2[(int)nq[q].z * 32 + p];
            }
#pragma unroll
            for (int q = 0; q < 4; q++)
                nq[q] = nd[min(beg + it + 16 + 2 * q + half, EEE - 1)];
        }
#pragma unroll
        for (int q = 0; q < 4; q++) {
            f32x2 tt = v02[q] * av + u1[q] * apv;
            float pa = tt.x + tt.y;
            pa += __shfl_xor(pa, 1);
            pa += __shfl_xor(pa, 2);
            e[q] = fmaxf(pa, 0.01f * pa);        // leaky_relu
        }
        if (it + 8 > n) {                        // tail chunk only (wave-uniform)
#pragma unroll
            for (int q = 0; q < 4; q++)
                if (it + 2 * q + half >= n) e[q] = -3.4e38f;
        }
        float mx = fmaxf(fmaxf(e[0], e[1]), fmaxf(e[2], e[3]));
        float mn = fmaxf(m, fmaxf(mx, __shfl_xor(mx, 32)));
        float alpha = __expf(m - mn);
        s *= alpha; A02 *= alpha; A1 *= alpha;
        float wl = 0.f;
#pragma unroll
        for (int q = 0; q < 4; q++) {
            float w = __expf(e[q] - mn);
            wl += w;
            A02 += v02[q] * w;
            A1  += u1[q] * w;
        }
        s += wl + __shfl_xor(wl, 32);
        m = mn;
    }
    float Sx = A02.x + __shfl_xor(A02.x, 32);
    float Sy = A02.y + __shfl_xor(A02.y, 32);
    float Tx = A1.x + __shfl_xor(A1.x, 32);
    float Ty = A1.y + __shfl_xor(A1.y, 32);
    float inv = (1.f / 3.f) / (s + 1e-9f);
    float vx = (Sx + rvx * Tx - rvy * Ty) * inv;
    float vy = (Sy + rvx * Ty + rvy * Tx) * inv;
    vx = vx > 0.f ? vx : __expf(vx) - 1.f;       // ELU
    vy = vy > 0.f ? vy : __expf(vy) - 1.f;
    if (half == 0)
        ((float2*)ret)[((long)combo * BBB + t) * 32 + p] = make_float2(vx, vy);
}

// ---------------- semantic score GEMM: s_acc[combo] = sum_b tanh(ret_b @ w1 + b1) @ w2 ----------------
__global__ __launch_bounds__(256) void sem_kernel(
    const float* __restrict__ ret,
    const float* __restrict__ su_w1, const float* __restrict__ su_b1, const float* __restrict__ su_w2,
    const float* __restrict__ si_w1, const float* __restrict__ si_b1, const float* __restrict__ si_w2,
    float* __restrict__ s_acc)
{
    int combo = blockIdx.y;
    int side = combo >> 1;
    const float* w1 = side ? si_w1 : su_w1;
    const float* b1 = side ? si_b1 : su_b1;
    const float* w2 = side ? si_w2 : su_w2;
    __shared__ float vs[64][68];
    __shared__ float w1s[64][128];
    int tid = threadIdx.x;
    int rowbase = blockIdx.x * 64;
    const float4* r4 = (const float4*)ret;
    for (int li = tid; li < 1024; li += 256) {
        int r = li >> 4, c4 = li & 15;
        float4 v = r4[((long)combo * BBB + rowbase + r) * 16 + c4];
        *(float4*)&vs[r][c4 * 4] = v;
    }
    const float4* w14 = (const float4*)w1;
    for (int li = tid; li < 2048; li += 256) {
        float4 v = w14[li];
        *(float4*)&w1s[li >> 5][(li & 31) * 4] = v;
    }
    __syncthreads();
    int ct = tid & 15, rt = tid >> 4;
    float acc[4][8];
#pragma unroll
    for (int cc = 0; cc < 8; cc++) {
        float b = b1[8 * ct + cc];
#pragma unroll
        for (int j = 0; j < 4; j++) acc[j][cc] = b;
    }
    for (int k = 0; k < 64; k += 4) {
        float4 xv[4];
#pragma unroll
        for (int j = 0; j < 4; j++) xv[j] = *(const float4*)&vs[4 * rt + j][k];
#pragma unroll
        for (int kk = 0; kk < 4; kk++) {
            float4 wv0 = *(const float4*)&w1s[k + kk][8 * ct];
            float4 wv1 = *(const float4*)&w1s[k + kk][8 * ct + 4];
#pragma unroll
            for (int j = 0; j < 4; j++) {
                float xx = kk == 0 ? xv[j].x : kk == 1 ? xv[j].y : kk == 2 ? xv[j].z : xv[j].w;
                acc[j][0] = fmaf(xx, wv0.x, acc[j][0]);
                acc[j][1] = fmaf(xx, wv0.y, acc[j][1]);
                acc[j][2] = fmaf(xx, wv0.z, acc[j][2]);
                acc[j][3] = fmaf(xx, wv0.w, acc[j][3]);
                acc[j][4] = fmaf(xx, wv1.x, acc[j][4]);
                acc[j][5] = fmaf(xx, wv1.y, acc[j][5]);
                acc[j][6] = fmaf(xx, wv1.z, acc[j][6]);
                acc[j][7] = fmaf(xx, wv1.w, acc[j][7]);
            }
        }
    }
    float tot = 0.f;
#pragma unroll
    for (int cc = 0; cc < 8; cc++) {
        float w2v = w2[8 * ct + cc];
#pragma unroll
        for (int j = 0; j < 4; j++) tot += fast_tanh(acc[j][cc]) * w2v;
    }
    for (int off = 32; off; off >>= 1) tot += __shfl_xor(tot, off);
    __shared__ float red[4];
    int lane = tid & 63, wid = tid >> 6;
    if (lane == 0) red[wid] = tot;
    __syncthreads();
    if (tid == 0) atomicAdd(&s_acc[combo], red[0] + red[1] + red[2] + red[3]);
}

// ---------------- final product MLP + softmax (beta inline, GEMM-tiled) ----------------
__global__ __launch_bounds__(256) void final_kernel(
    const float* __restrict__ ret, const float* __restrict__ s_acc,
    const float* __restrict__ cw1, const float* __restrict__ cb1, const float* __restrict__ cw2,
    float* __restrict__ outp)
{
    float s0 = s_acc[0] * (1.f / BBB), s1 = s_acc[1] * (1.f / BBB);
    float s2 = s_acc[2] * (1.f / BBB), s3 = s_acc[3] * (1.f / BBB);
    float mu = fmaxf(s0, s1);
    float e0 = __expf(s0 - mu), e1 = __expf(s1 - mu);
    float bu0 = e0 / (e0 + e1), bu1 = e1 / (e0 + e1);
    float mi = fmaxf(s2, s3);
    float f0 = __expf(s2 - mi), f1 = __expf(s3 - mi);
    float bi0 = f0 / (f0 + f1), bi1 = f1 / (f0 + f1);

    __shared__ float xsld[64][68];
    __shared__ float w1s[64][128];
    int tid = threadIdx.x;
    int rowbase = blockIdx.x * 64;
    const float4* r4 = (const float4*)ret;
    for (int li = tid; li < 1024; li += 256) {
        int r = li >> 4, c4 = li & 15;
        float4 a = r4[((long)0 * BBB + rowbase + r) * 16 + c4];
        float4 b = r4[((long)1 * BBB + rowbase + r) * 16 + c4];
        float4 cc = r4[((long)2 * BBB + rowbase + r) * 16 + c4];
        float4 d = r4[((long)3 * BBB + rowbase + r) * 16 + c4];
        float4 xv;
        xv.x = (bu0 * a.x + bu1 * b.x) * (bi0 * cc.x + bi1 * d.x);
        xv.y = (bu0 * a.y + bu1 * b.y) * (bi0 * cc.y + bi1 * d.y);
        xv.z = (bu0 * a.z + bu1 * b.z) * (bi0 * cc.z + bi1 * d.z);
        xv.w = (bu0 * a.w + bu1 * b.w) * (bi0 * cc.w + bi1 * d.w);
        *(float4*)&xsld[r][c4 * 4] = xv;
    }
    const float4* w14 = (const float4*)cw1;
    for (int li = tid; li < 2048; li += 256) {
        float4 v = w14[li];
        *(float4*)&w1s[li >> 5][(li & 31) * 4] = v;
    }
    __syncthreads();
    int ct = tid & 15, rt = tid >> 4;
    float acc[4][8];
#pragma unroll
    for (int cc = 0; cc < 8; cc++) {
        float b = cb1[8 * ct + cc];
#pragma unroll
        for (int j = 0; j < 4; j++) acc[j][cc] = b;
    }
    for (int k = 0; k < 64; k += 4) {
        float4 xv[4];
#pragma unroll
        for (int j = 0; j < 4; j++) xv[j] = *(const float4*)&xsld[4 * rt + j][k];
#pragma unroll
        for (int kk = 0; kk < 4; kk++) {
            float4 wv0 = *(const float4*)&w1s[k + kk][8 * ct];
            float4 wv1 = *(const float4*)&w1s[k + kk][8 * ct + 4];
#pragma unroll
            for (int j = 0; j < 4; j++) {
                float xx = kk == 0 ? xv[j].x : kk == 1 ? xv[j].y : kk == 2 ? xv[j].z : xv[j].w;
                acc[j][0] = fmaf(xx, wv0.x, acc[j][0]);
                acc[j][1] = fmaf(xx, wv0.y, acc[j][1]);
                acc[j][2] = fmaf(xx, wv0.z, acc[j][2]);
                acc[j][3] = fmaf(xx, wv0.w, acc[j][3]);
                acc[j][4] = fmaf(xx, wv1.x, acc[j][4]);
                acc[j][5] = fmaf(xx, wv1.y, acc[j][5]);
                acc[j][6] = fmaf(xx, wv1.z, acc[j][6]);
                acc[j][7] = fmaf(xx, wv1.w, acc[j][7]);
            }
        }
    }
    float pp0[4], pp1[4];
#pragma unroll
    for (int j = 0; j < 4; j++) { pp0[j] = 0.f; pp1[j] = 0.f; }
#pragma unroll
    for (int cc = 0; cc < 8; cc++) {
        int col = 8 * ct + cc;
        float c0 = cw2[col * 2], c1 = cw2[col * 2 + 1];
#pragma unroll
        for (int j = 0; j < 4; j++) {
            float h = fmaxf(acc[j][cc], 0.f);
            pp0[j] = fmaf(h, c0, pp0[j]);
            pp1[j] = fmaf(h, c1, pp1[j]);
        }
    }
    __syncthreads();
    float2* red = (float2*)xsld;
#pragma unroll
    for (int j = 0; j < 4; j++)
        red[(4 * rt + j) * 16 + ct] = make_float2(pp0[j], pp1[j]);
    __syncthreads();
    if (tid < 64) {
        float q0 = 0.f, q1 = 0.f;
        for (int i = 0; i < 16; i++) {
            float2 e = red[tid * 16 + i];
            q0 += e.x; q1 += e.y;
        }
        float mx = fmaxf(q0, q1);
        float a0 = __expf(q0 - mx), a1 = __expf(q1 - mx);
        float dn = a0 + a1;
        outp[(rowbase + tid) * 2] = a0 / dn;
        outp[(rowbase + tid) * 2 + 1] = a1 / dn;
    }
}

extern "C" void kernel_launch(void* const* d_in, const int* in_sizes, int n_in,
                              void* d_out, int out_size, void* d_ws, size_t ws_size,
                              hipStream_t stream)
{
    const float* feats0 = (const float*)d_in[0];
    const float* feats1 = (const float*)d_in[1];
    const float* t0_pw = (const float*)d_in[2];
    const float* t0_pb = (const float*)d_in[3];
    const float* t0_w2 = (const float*)d_in[4];
    const float* t0_b2 = (const float*)d_in[5];
    const float* t0_g  = (const float*)d_in[6];
    const float* t0_be = (const float*)d_in[7];
    const float* t1_pw = (const float*)d_in[8];
    const float* t1_pb = (const float*)d_in[9];
    const float* t1_w2 = (const float*)d_in[10];
    const float* t1_b2 = (const float*)d_in[11];
    const float* t1_g  = (const float*)d_in[12];
    const float* t1_be = (const float*)d_in[13];
    const float* r_vec = (const float*)d_in[14];
    const float* attn_user = (const float*)d_in[15];
    const float* attn_item = (const float*)d_in[16];
    const float* su_w1 = (const float*)d_in[17];
    const float* su_b1 = (const float*)d_in[18];
    const float* su_w2 = (const float*)d_in[19];
    const float* si_w1 = (const float*)d_in[20];
    const float* si_b1 = (const float*)d_in[21];
    const float* si_w2 = (const float*)d_in[22];
    const float* cw1 = (const float*)d_in[23];
    const float* cb1 = (const float*)d_in[24];
    const float* cw2 = (const float*)d_in[25];
    const int* idx0 = (const int*)d_in[26];
    const int* idx1 = (const int*)d_in[27];
    const int* emi_user = (const int*)d_in[28];
    const int* tgt_user = (const int*)d_in[29];
    const int* emi_item = (const int*)d_in[30];
    const int* tgt_item = (const int*)d_in[31];
    float* outp = (float*)d_out;

    // workspace layout (256B aligned)
    char* ws = (char*)d_ws;
    __hip_bfloat16* feat = (__hip_bfloat16*)(ws + 0);   // 5,120,000
    int*     cnt32p  = (int*)(ws + 5120000);            // 16,384 (128 counters, 128B stride)
    int*     cur32cnt= (int*)(ws + 5136384);            // 512
    float*   s_acc   = (float*)(ws + 5136896);          // 256  (memset covers all three: 17,152B)
    int*     offs    = (int*)(ws + 5137408);            // 131,088 -> pad
    ushort4* binbuf  = (ushort4*)(ws + 5268736);        // 6,400,000
    ushort4* nodes   = (ushort4*)(ws + 11668736);       // 6,400,000
    float*   ret_buf = (float*)(ws + 18068736);         // 8,388,608
    __bf16*  wprep   = (__bf16*)(ws + 26457344);        // 262,144  (end ~26.7 MB)
    // w2prep (32KB) aliases the start of `nodes`: written by prep_hist, read by tower
    // (tower_binA), then overwritten by binB which runs strictly after. binA writes
    // only binbuf, so the concurrent tower reads are race-free.
    __bf16*  w2prep  = (__bf16*)(ws + 11668736);

    hipMemsetAsync(cnt32p, 0, 16384 + 512 + 256, stream);

    prep_hist<<<36 + 4 * ((EEE + HCHUNK - 1) / HCHUNK), 256, 0, stream>>>(
        t0_pw, t1_pw, t0_w2, t1_w2, wprep, w2prep, tgt_user, tgt_item, cnt32p);

    tower_binA<<<2500 + 4 * ((EEE + CHUNKF - 1) / CHUNKF), 128, 0, stream>>>(
        feats0, feats1, wprep, w2prep, t0_pb, t1_pb,
        t0_b2, t1_b2, t0_g, t1_g, t0_be, t1_be, idx0, idx1, feat,
        tgt_user, tgt_item, emi_user, emi_item, cnt32p, cur32cnt, binbuf);

    binB_kernel<<<dim3(32, 4), 512, 0, stream>>>(cnt32p, offs, binbuf, nodes);

    flash_mp<<<dim3(BBB / 4, 4), 256, 0, stream>>>(feat, nodes, offs, r_vec,
                                                   attn_user, attn_item, ret_buf);

    sem_kernel<<<dim3(BBB / 64, 4), 256, 0, stream>>>(ret_buf, su_w1, su_b1, su_w2,
                                                      si_w1, si_b1, si_w2, s_acc);
    final_kernel<<<BBB / 64, 256, 0, stream>>>(ret_buf, s_acc, cw1, cb1, cw2, outp);
}